// Round 14
// baseline (255.996 us; speedup 1.0000x reference)
//
#include <hip/hip_runtime.h>
#include <hip/hip_bf16.h>
#include <type_traits>

// ---------------------------------------------------------------------------
// CausalSelfAttention: x[4,2048,1024] f32, w_qkv[3072,1024], w_out[1024,1024]
// cvt(bf16) -> GEMM qkv (256^2 counted-vmcnt) -> flash attn (32x32 MFMA,
// in-register P) -> GEMM out (256x128 counted-vmcnt, f32)
// ---------------------------------------------------------------------------

typedef __attribute__((ext_vector_type(8))) short bf16x8;
typedef __attribute__((ext_vector_type(4))) float f32x4;
typedef __attribute__((ext_vector_type(16))) float f32x16;
typedef __attribute__((ext_vector_type(4))) int i32x4;

#define LDS_AS(p) ((__attribute__((address_space(3))) void*)(p))
#define GLB_AS(p) ((const __attribute__((address_space(1))) void*)(p))

// ------------------- fp32 -> bf16 (all three inputs, one launch) -----------
__global__ __launch_bounds__(256) void cvt3_f32_bf16(const float* __restrict__ a,
                                                     const float* __restrict__ b,
                                                     const float* __restrict__ c,
                                                     __hip_bfloat16* __restrict__ oa,
                                                     __hip_bfloat16* __restrict__ ob,
                                                     __hip_bfloat16* __restrict__ oc,
                                                     int na4, int nb4, int nc4) {
  const int ntot = na4 + nb4 + nc4;
  for (int i = blockIdx.x * 256 + threadIdx.x; i < ntot; i += gridDim.x * 256) {
    int j = i;
    const float* in; __hip_bfloat16* out;
    if (j < na4) { in = a; out = oa; }
    else if (j < na4 + nb4) { in = b; out = ob; j -= na4; }
    else { in = c; out = oc; j -= na4 + nb4; }
    float4 v = reinterpret_cast<const float4*>(in)[j];
    __hip_bfloat16 b0 = __float2bfloat16(v.x);
    __hip_bfloat16 b1 = __float2bfloat16(v.y);
    __hip_bfloat16 b2 = __float2bfloat16(v.z);
    __hip_bfloat16 b3 = __float2bfloat16(v.w);
    ushort4 u;
    u.x = *reinterpret_cast<unsigned short*>(&b0);
    u.y = *reinterpret_cast<unsigned short*>(&b1);
    u.z = *reinterpret_cast<unsigned short*>(&b2);
    u.w = *reinterpret_cast<unsigned short*>(&b3);
    reinterpret_cast<ushort4*>(out)[j] = u;
  }
}

// ---------------- GEMM 256^2: C[M,N] = A[M,K] * B[N,K]^T, bf16 out ---------
__global__ __launch_bounds__(512, 1) void gemm_bt256(const __hip_bfloat16* __restrict__ A,
                                                     const __hip_bfloat16* __restrict__ B,
                                                     __hip_bfloat16* __restrict__ C,
                                                     int M, int N, int K) {
  __shared__ __hip_bfloat16 As[2][256 * 64];
  __shared__ __hip_bfloat16 Bs[2][256 * 64];
  const int tid = threadIdx.x;
  const int lane = tid & 63;
  const int wid = tid >> 6;
  const int l15 = lane & 15, l4 = lane >> 4;
  const int wr = wid >> 2;
  const int wc = wid & 3;
  const int m0 = blockIdx.x * 256, n0 = blockIdx.y * 256;
  const int NT = K >> 6;
  f32x4 acc[8][4] = {};

#define STAGE256(buf, kt)                                                            \
  do {                                                                               \
    _Pragma("unroll")                                                                \
    for (int i_ = 0; i_ < 4; ++i_) {                                                 \
      const int slot_ = i_ * 512 + tid;                                              \
      const int row_ = slot_ >> 3, c8_ = slot_ & 7;                                  \
      const int gc_ = (c8_ ^ (row_ & 7)) * 8;                                        \
      __builtin_amdgcn_global_load_lds(                                              \
          GLB_AS(A + (size_t)(m0 + row_) * K + (kt) + gc_),                          \
          LDS_AS((char*)As[buf] + slot_ * 16), 16, 0, 0);                            \
      __builtin_amdgcn_global_load_lds(                                              \
          GLB_AS(B + (size_t)(n0 + row_) * K + (kt) + gc_),                          \
          LDS_AS((char*)Bs[buf] + slot_ * 16), 16, 0, 0);                            \
    }                                                                                \
  } while (0)

  STAGE256(0, 0);
  if (NT > 1) STAGE256(1, 64);

  for (int t = 0; t < NT; ++t) {
    const int cur = t & 1;
    if (t < NT - 1) asm volatile("s_waitcnt vmcnt(8)" ::: "memory");
    else            asm volatile("s_waitcnt vmcnt(0)" ::: "memory");
    __builtin_amdgcn_s_barrier();
    asm volatile("" ::: "memory");

#pragma unroll
    for (int q = 0; q < 4; ++q) {
      const int mbase = wr * 128 + (q & 1) * 64;
      const int nbase = wc * 64 + (q >> 1) * 32;
      bf16x8 af[4][2], bfr[2][2];
#pragma unroll
      for (int mi = 0; mi < 4; ++mi)
#pragma unroll
        for (int kk = 0; kk < 2; ++kk) {
          const int r = mbase + mi * 16 + l15;
          af[mi][kk] = *reinterpret_cast<const bf16x8*>(
              &As[cur][r * 64 + (((kk * 4 + l4) ^ (r & 7)) * 8)]);
        }
#pragma unroll
      for (int nj = 0; nj < 2; ++nj)
#pragma unroll
        for (int kk = 0; kk < 2; ++kk) {
          const int r = nbase + nj * 16 + l15;
          bfr[nj][kk] = *reinterpret_cast<const bf16x8*>(
              &Bs[cur][r * 64 + (((kk * 4 + l4) ^ (r & 7)) * 8)]);
        }
      __builtin_amdgcn_s_setprio(1);
#pragma unroll
      for (int mi = 0; mi < 4; ++mi)
#pragma unroll
        for (int nj = 0; nj < 2; ++nj) {
          acc[(q & 1) * 4 + mi][(q >> 1) * 2 + nj] = __builtin_amdgcn_mfma_f32_16x16x32_bf16(
              af[mi][0], bfr[nj][0], acc[(q & 1) * 4 + mi][(q >> 1) * 2 + nj], 0, 0, 0);
          acc[(q & 1) * 4 + mi][(q >> 1) * 2 + nj] = __builtin_amdgcn_mfma_f32_16x16x32_bf16(
              af[mi][1], bfr[nj][1], acc[(q & 1) * 4 + mi][(q >> 1) * 2 + nj], 0, 0, 0);
        }
      __builtin_amdgcn_s_setprio(0);
    }
    asm volatile("" ::: "memory");
    __builtin_amdgcn_s_barrier();
    asm volatile("" ::: "memory");
    if (t + 2 < NT) STAGE256(cur, (t + 2) << 6);
  }
#undef STAGE256

#pragma unroll
  for (int mi = 0; mi < 8; ++mi)
#pragma unroll
    for (int ni = 0; ni < 4; ++ni)
#pragma unroll
      for (int j = 0; j < 4; ++j) {
        const int m = m0 + wr * 128 + mi * 16 + l4 * 4 + j;
        const int n = n0 + wc * 64 + ni * 16 + l15;
        C[(size_t)m * N + n] = __float2bfloat16(acc[mi][ni][j]);
      }
}

// ------------- GEMM 256x128: C[M,N] = A[M,K]*B[N,K]^T, f32 out -------------
__global__ __launch_bounds__(512, 1) void gemm_bt256x128f(const __hip_bfloat16* __restrict__ A,
                                                          const __hip_bfloat16* __restrict__ B,
                                                          float* __restrict__ C,
                                                          int M, int N, int K) {
  __shared__ __hip_bfloat16 As[2][256 * 64];
  __shared__ __hip_bfloat16 Bs[2][128 * 64];
  const int tid = threadIdx.x;
  const int lane = tid & 63;
  const int wid = tid >> 6;
  const int l15 = lane & 15, l4 = lane >> 4;
  const int wr = (wid >> 1) * 64;
  const int wc = (wid & 1) * 64;
  const int m0 = blockIdx.x * 256, n0 = blockIdx.y * 128;
  const int NT = K >> 6;
  f32x4 acc[4][4] = {};

#define STAGE2(buf, kt)                                                              \
  do {                                                                               \
    _Pragma("unroll")                                                                \
    for (int i_ = 0; i_ < 4; ++i_) {                                                 \
      const int slot_ = i_ * 512 + tid;                                              \
      const int row_ = slot_ >> 3, c8_ = slot_ & 7;                                  \
      const int gc_ = (c8_ ^ (row_ & 7)) * 8;                                        \
      __builtin_amdgcn_global_load_lds(                                              \
          GLB_AS(A + (size_t)(m0 + row_) * K + (kt) + gc_),                          \
          LDS_AS((char*)As[buf] + slot_ * 16), 16, 0, 0);                            \
    }                                                                                \
    _Pragma("unroll")                                                                \
    for (int i_ = 0; i_ < 2; ++i_) {                                                 \
      const int slot_ = i_ * 512 + tid;                                              \
      const int row_ = slot_ >> 3, c8_ = slot_ & 7;                                  \
      const int gc_ = (c8_ ^ (row_ & 7)) * 8;                                        \
      __builtin_amdgcn_global_load_lds(                                              \
          GLB_AS(B + (size_t)(n0 + row_) * K + (kt) + gc_),                          \
          LDS_AS((char*)Bs[buf] + slot_ * 16), 16, 0, 0);                            \
    }                                                                                \
  } while (0)

  STAGE2(0, 0);
  if (NT > 1) STAGE2(1, 64);

  for (int t = 0; t < NT; ++t) {
    const int cur = t & 1;
    if (t < NT - 1) asm volatile("s_waitcnt vmcnt(6)" ::: "memory");
    else            asm volatile("s_waitcnt vmcnt(0)" ::: "memory");
    __builtin_amdgcn_s_barrier();
    asm volatile("" ::: "memory");

#pragma unroll
    for (int kk = 0; kk < 2; ++kk) {
      bf16x8 af[4], bfr[4];
#pragma unroll
      for (int mi = 0; mi < 4; ++mi) {
        const int r = wr + mi * 16 + l15;
        af[mi] = *reinterpret_cast<const bf16x8*>(
            &As[cur][r * 64 + (((kk * 4 + l4) ^ (r & 7)) * 8)]);
      }
#pragma unroll
      for (int ni = 0; ni < 4; ++ni) {
        const int r = wc + ni * 16 + l15;
        bfr[ni] = *reinterpret_cast<const bf16x8*>(
            &Bs[cur][r * 64 + (((kk * 4 + l4) ^ (r & 7)) * 8)]);
      }
      __builtin_amdgcn_s_setprio(1);
#pragma unroll
      for (int mi = 0; mi < 4; ++mi)
#pragma unroll
        for (int ni = 0; ni < 4; ++ni)
          acc[mi][ni] = __builtin_amdgcn_mfma_f32_16x16x32_bf16(af[mi], bfr[ni], acc[mi][ni], 0, 0, 0);
      __builtin_amdgcn_s_setprio(0);
    }
    asm volatile("" ::: "memory");
    __builtin_amdgcn_s_barrier();
    asm volatile("" ::: "memory");
    if (t + 2 < NT) STAGE2(cur, (t + 2) << 6);
  }
#undef STAGE2

#pragma unroll
  for (int mi = 0; mi < 4; ++mi)
#pragma unroll
    for (int ni = 0; ni < 4; ++ni)
#pragma unroll
      for (int j = 0; j < 4; ++j) {
        const int m = m0 + wr + mi * 16 + l4 * 4 + j;
        const int n = n0 + wc + ni * 16 + l15;
        C[(size_t)m * N + n] = acc[mi][ni][j];
      }
}

// --------------------------- causal flash attn (32x32) ---------------------
// R6 skeleton (staging/dbuf/wave-map/defer-max) with 32x32x16 MFMA compute.
// Per wave: 64 q-rows = 2 chunks of 32. Swapped QK^T (A=K,B=Q) -> lane holds
// full kv-row for q=lane&31 (D-layout m74/m101: col=lane&31,
// row=(reg&3)+8*(reg>>2)+4*(lane>>5)). Softmax: 1 shfl_xor(32) per reduce.
// P -> PV B-operand built IN REGISTERS (cvt_pk + shfl_xor(32) half-exchange);
// no P LDS roundtrip, no lgkm fences. (512,1): grid 256 = 1 block/CU anyway,
// lifts reg cap to 256 (R7 lesson: 2nd arg acts as blocks/CU).
__global__ __launch_bounds__(512, 1) void attn_causal(const __hip_bfloat16* __restrict__ qkv,
                                                      __hip_bfloat16* __restrict__ o) {
  constexpr int T = 2048, F = 3072, C = 1024;
  __shared__ __hip_bfloat16 Ks[2][64 * 72];     // K tile  [kv][d], pad 72
  __shared__ __hip_bfloat16 Vts[2][64 * 72];    // V^T tile [d][kv], pad 72
  const int tid = threadIdx.x;
  const int wid = tid >> 6, lane = tid & 63;
  const int l31 = lane & 31, lh = lane >> 5;    // half-wave index
  const int x = blockIdx.x, h = blockIdx.y, b = blockIdx.z;
  const int qt = (wid < 4) ? x : (7 - x);
  const int nt = 4 * (7 - x) + 4;
  const int tmax = 4 * qt + (wid & 3);
  const int hoff = h * 64;
  const __hip_bfloat16* base = qkv + (size_t)b * T * F;
  const int Q0 = qt * 256 + (wid & 3) * 64;

  constexpr float SC = 0.125f * 1.44269504088896f;  // 1/sqrt(64)*log2(e)

  // Q frags (B operand), prescaled: aq[c][s] = Q[Q0+c*32+l31][s*16+lh*8 ..+7]
  bf16x8 aq[2][4];
#pragma unroll
  for (int c = 0; c < 2; ++c)
#pragma unroll
    for (int s = 0; s < 4; ++s) {
      bf16x8 q = *reinterpret_cast<const bf16x8*>(
          base + (size_t)(Q0 + c * 32 + l31) * F + hoff + s * 16 + lh * 8);
#pragma unroll
      for (int e = 0; e < 8; ++e) {
        const unsigned short raw = (unsigned short)q[e];
        const float fv = __uint_as_float((unsigned)raw << 16) * SC;
        __hip_bfloat16 qs = __float2bfloat16(fv);
        q[e] = *reinterpret_cast<short*>(&qs);
      }
      aq[c][s] = q;
    }

  f32x16 acc[2][2] = {};  // [chunk][d-half]: O^T[d][q=l31]
  float mrun[2], lrun[2];
#pragma unroll
  for (int c = 0; c < 2; ++c) { mrun[c] = -1e30f; lrun[c] = 0.f; }

  // staging roles: waves 0-3 stage V (rotated dword writes), waves 4-7 stage K
  const int sV = tid;
  const int sK = tid - 256;
  bf16x8 sreg0, sreg1;
  if (wid < 4) {
    const size_t vr = (size_t)(2 * (sV >> 3)) * F + hoff + 2 * C + (sV & 7) * 8;
    sreg0 = *reinterpret_cast<const bf16x8*>(base + vr);
    sreg1 = *reinterpret_cast<const bf16x8*>(base + vr + F);
  } else {
    sreg0 = *reinterpret_cast<const bf16x8*>(base + (size_t)(sK >> 3) * F + hoff + C + (sK & 7) * 8);
    sreg1 = *reinterpret_cast<const bf16x8*>(base + (size_t)(32 + (sK >> 3)) * F + hoff + C + (sK & 7) * 8);
  }

  for (int t = 0; t < nt; ++t) {
    const int cur = t & 1;
    if (wid < 4) {
      const unsigned short* a0 = reinterpret_cast<const unsigned short*>(&sreg0);
      const unsigned short* a1 = reinterpret_cast<const unsigned short*>(&sreg1);
      const int c8 = sV & 7, r2 = sV >> 3;
      unsigned pk[8], tw[8], pkr[8];
#pragma unroll
      for (int j = 0; j < 8; ++j) pk[j] = (unsigned)a0[j] | ((unsigned)a1[j] << 16);
#pragma unroll
      for (int j = 0; j < 8; ++j) tw[j] = (c8 & 4) ? pk[(j + 4) & 7] : pk[j];
#pragma unroll
      for (int j = 0; j < 8; ++j) pkr[j] = (c8 & 2) ? tw[(j + 2) & 7] : tw[j];
#pragma unroll
      for (int j = 0; j < 8; ++j) tw[j] = (c8 & 1) ? pkr[(j + 1) & 7] : pkr[j];
#pragma unroll
      for (int jj = 0; jj < 8; ++jj) {
        const int d = c8 * 8 + ((jj + c8) & 7);
        *reinterpret_cast<unsigned*>(&Vts[cur][d * 72 + 2 * r2]) = tw[jj];
      }
    } else {
      *reinterpret_cast<bf16x8*>(&Ks[cur][(sK >> 3) * 72 + (sK & 7) * 8]) = sreg0;
      *reinterpret_cast<bf16x8*>(&Ks[cur][(32 + (sK >> 3)) * 72 + (sK & 7) * 8]) = sreg1;
    }
    __syncthreads();
    if (t + 1 < nt) {
      const int kn = (t + 1) * 64;
      if (wid < 4) {
        const size_t vr = (size_t)(kn + 2 * (sV >> 3)) * F + hoff + 2 * C + (sV & 7) * 8;
        sreg0 = *reinterpret_cast<const bf16x8*>(base + vr);
        sreg1 = *reinterpret_cast<const bf16x8*>(base + vr + F);
      } else {
        sreg0 = *reinterpret_cast<const bf16x8*>(base + (size_t)(kn + (sK >> 3)) * F + hoff + C + (sK & 7) * 8);
        sreg1 = *reinterpret_cast<const bf16x8*>(base + (size_t)(kn + 32 + (sK >> 3)) * F + hoff + C + (sK & 7) * 8);
      }
    }
    if (t > tmax) continue;
    const bool diag = (t == tmax);

    // ---- hoist K / V^T fragments (A operands, rows = lane&31) ----
    bf16x8 ka[2][4], va[2][4];
#pragma unroll
    for (int hh = 0; hh < 2; ++hh)
#pragma unroll
      for (int s = 0; s < 4; ++s)
        ka[hh][s] = *reinterpret_cast<const bf16x8*>(
            &Ks[cur][(hh * 32 + l31) * 72 + s * 16 + lh * 8]);
#pragma unroll
    for (int dh = 0; dh < 2; ++dh)
#pragma unroll
      for (int s = 0; s < 4; ++s)
        va[dh][s] = *reinterpret_cast<const bf16x8*>(
            &Vts[cur][(dh * 32 + l31) * 72 + s * 16 + lh * 8]);

#pragma unroll
    for (int c = 0; c < 2; ++c) {
      // ---- S^T = K Q^T : lane holds S[q=l31][full 64-kv row] ----
      f32x16 sh0 = {}, sh1 = {};
#pragma unroll
      for (int s = 0; s < 4; ++s)
        sh0 = __builtin_amdgcn_mfma_f32_32x32x16_bf16(ka[0][s], aq[c][s], sh0, 0, 0, 0);
#pragma unroll
      for (int s = 0; s < 4; ++s)
        sh1 = __builtin_amdgcn_mfma_f32_32x32x16_bf16(ka[1][s], aq[c][s], sh1, 0, 0, 0);

      // ---- causal mask (diag tile only; tile-local) ----
      if (diag) {
        const int ql = c * 32 + l31;
#pragma unroll
        for (int r = 0; r < 16; ++r) {
          const int kvl = (r & 3) + 8 * (r >> 2) + 4 * lh;
          sh0[r] = (kvl <= ql) ? sh0[r] : -1e30f;
          sh1[r] = (kvl + 32 <= ql) ? sh1[r] : -1e30f;
        }
      }

      // ---- online softmax: in-lane 31-op tree + ONE shfl_xor(32) ----
      float mt = -1e30f;
#pragma unroll
      for (int r = 0; r < 16; ++r) mt = fmaxf(mt, fmaxf(sh0[r], sh1[r]));
      mt = fmaxf(mt, __shfl_xor(mt, 32, 64));
      const bool defer = __all(mt <= mrun[c] + 8.f);
      const float mnew = defer ? mrun[c] : fmaxf(mrun[c], mt);
      float rs = 0.f;
#pragma unroll
      for (int r = 0; r < 16; ++r) {
        const float p0 = exp2f(sh0[r] - mnew), p1 = exp2f(sh1[r] - mnew);
        sh0[r] = p0; sh1[r] = p1;
        rs += p0 + p1;
      }
      rs += __shfl_xor(rs, 32, 64);
      if (defer) {
        lrun[c] += rs;
      } else {
        const float sco = exp2f(mrun[c] - mnew);
        lrun[c] = lrun[c] * sco + rs;
        mrun[c] = mnew;
        acc[c][0] *= sco;
        acc[c][1] *= sco;
      }

      // ---- P -> PV B-operand in registers + PV ----
      // pb[s] = P[q=l31][kv = s*16 + lh*8 + 0..7]. Reg roles per 16-kv block:
      // X regs r0+0..3 (lo:kv+0..3 A-role / hi:kv+4..7 B-role),
      // Y regs r0+4..7 (lo:kv+8..11 B-role / hi:kv+12..15 A-role).
#pragma unroll
      for (int s = 0; s < 4; ++s) {
        const int r0 = (s & 1) * 8;
        unsigned pkX0, pkX1, pkY0, pkY1;
        if (s < 2) {
          asm("v_cvt_pk_bf16_f32 %0, %1, %2" : "=v"(pkX0) : "v"(sh0[r0 + 0]), "v"(sh0[r0 + 1]));
          asm("v_cvt_pk_bf16_f32 %0, %1, %2" : "=v"(pkX1) : "v"(sh0[r0 + 2]), "v"(sh0[r0 + 3]));
          asm("v_cvt_pk_bf16_f32 %0, %1, %2" : "=v"(pkY0) : "v"(sh0[r0 + 4]), "v"(sh0[r0 + 5]));
          asm("v_cvt_pk_bf16_f32 %0, %1, %2" : "=v"(pkY1) : "v"(sh0[r0 + 6]), "v"(sh0[r0 + 7]));
        } else {
          asm("v_cvt_pk_bf16_f32 %0, %1, %2" : "=v"(pkX0) : "v"(sh1[r0 + 0]), "v"(sh1[r0 + 1]));
          asm("v_cvt_pk_bf16_f32 %0, %1, %2" : "=v"(pkX1) : "v"(sh1[r0 + 2]), "v"(sh1[r0 + 3]));
          asm("v_cvt_pk_bf16_f32 %0, %1, %2" : "=v"(pkY0) : "v"(sh1[r0 + 4]), "v"(sh1[r0 + 5]));
          asm("v_cvt_pk_bf16_f32 %0, %1, %2" : "=v"(pkY1) : "v"(sh1[r0 + 6]), "v"(sh1[r0 + 7]));
        }
        // exchange B-role words across half-waves (lo sends Y, hi sends X)
        const int send0 = (int)(lh ? pkX0 : pkY0);
        const int send1 = (int)(lh ? pkX1 : pkY1);
        const unsigned recv0 = (unsigned)__shfl_xor(send0, 32, 64);
        const unsigned recv1 = (unsigned)__shfl_xor(send1, 32, 64);
        i32x4 pw;
        pw[0] = (int)(lh ? recv0 : pkX0);
        pw[1] = (int)(lh ? recv1 : pkX1);
        pw[2] = (int)(lh ? pkY0 : recv0);
        pw[3] = (int)(lh ? pkY1 : recv1);
        bf16x8 pb = *reinterpret_cast<bf16x8*>(&pw);
        acc[c][0] = __builtin_amdgcn_mfma_f32_32x32x16_bf16(va[0][s], pb, acc[c][0], 0, 0, 0);
        acc[c][1] = __builtin_amdgcn_mfma_f32_32x32x16_bf16(va[1][s], pb, acc[c][1], 0, 0, 0);
      }
    }
  }

  // ---- normalize + write: O[q=Q0+c*32+l31][d = dh*32+G*8+4*lh+0..3] ----
#pragma unroll
  for (int c = 0; c < 2; ++c) {
    const float inv = 1.0f / lrun[c];
    __hip_bfloat16* op = o + (size_t)((size_t)b * T + Q0 + c * 32 + l31) * C + hoff;
#pragma unroll
    for (int dh = 0; dh < 2; ++dh)
#pragma unroll
      for (int G = 0; G < 4; ++G) {
        unsigned w0, w1;
        const float e0 = acc[c][dh][4 * G + 0] * inv, e1 = acc[c][dh][4 * G + 1] * inv;
        const float e2 = acc[c][dh][4 * G + 2] * inv, e3 = acc[c][dh][4 * G + 3] * inv;
        asm("v_cvt_pk_bf16_f32 %0, %1, %2" : "=v"(w0) : "v"(e0), "v"(e1));
        asm("v_cvt_pk_bf16_f32 %0, %1, %2" : "=v"(w1) : "v"(e2), "v"(e3));
        const unsigned long long dw = (unsigned long long)w0 | ((unsigned long long)w1 << 32);
        *reinterpret_cast<unsigned long long*>(op + dh * 32 + G * 8 + 4 * lh) = dw;
      }
  }
}

// ------------------------------- launcher ----------------------------------
extern "C" void kernel_launch(void* const* d_in, const int* in_sizes, int n_in,
                              void* d_out, int out_size, void* d_ws, size_t ws_size,
                              hipStream_t stream) {
  const float* x = (const float*)d_in[0];
  const float* w_qkv = (const float*)d_in[1];
  const float* w_out = (const float*)d_in[2];
  float* out = (float*)d_out;

  constexpr int B = 4, T = 2048, C = 1024, F = 3 * C;
  constexpr int M = B * T;

  __hip_bfloat16* xb = (__hip_bfloat16*)d_ws;            // M*C
  __hip_bfloat16* wqkvb = xb + (size_t)M * C;            // F*C
  __hip_bfloat16* woutb = wqkvb + (size_t)F * C;         // C*C
  __hip_bfloat16* qkvb = woutb + (size_t)C * C;          // M*F
  __hip_bfloat16* attnb = qkvb + (size_t)M * F;          // M*C

  constexpr int na4 = M * C / 4, nb4 = F * C / 4, nc4 = C * C / 4;
  cvt3_f32_bf16<<<2048, 256, 0, stream>>>(x, w_qkv, w_out, xb, wqkvb, woutb, na4, nb4, nc4);

  gemm_bt256<<<dim3(M / 256, F / 256), 512, 0, stream>>>(xb, wqkvb, qkvb, M, F, C);

  attn_causal<<<dim3(4, 16, B), 512, 0, stream>>>(qkvb, attnb);

  gemm_bt256x128f<<<dim3(M / 256, C / 128), 512, 0, stream>>>(attnb, woutb, out, M, C, C);
}

// Round 16
// 220.815 us; speedup vs baseline: 1.1593x; 1.1593x over previous
//
#include <hip/hip_runtime.h>
#include <hip/hip_bf16.h>
#include <type_traits>

// ---------------------------------------------------------------------------
// CausalSelfAttention: x[4,2048,1024] f32, w_qkv[3072,1024], w_out[1024,1024]
// Pipeline: cvt(bf16) -> GEMM qkv (256^2 counted-vmcnt) -> causal flash attn
//           (16x16, R6 config) -> GEMM out (256x128 counted-vmcnt, f32)
// R15 race fix (rule #18): raw s_barrier does NOT drain lgkm, and hipcc can
// sink register-only MFMAs (plus their guarding lgkmcnt waits) past
// memory-clobber asm and the barrier -> a wave could signal the barrier with
// ds_reads pending while another wave's STAGE overwrote the buffer.
// Fix: explicit s_waitcnt lgkmcnt(0) + sched_barrier(0) BEFORE barrier2.
// ---------------------------------------------------------------------------

typedef __attribute__((ext_vector_type(8))) short bf16x8;
typedef __attribute__((ext_vector_type(4))) float f32x4;

#define LDS_AS(p) ((__attribute__((address_space(3))) void*)(p))
#define GLB_AS(p) ((const __attribute__((address_space(1))) void*)(p))

// ------------------- fp32 -> bf16 (all three inputs, one launch) -----------
__global__ __launch_bounds__(256) void cvt3_f32_bf16(const float* __restrict__ a,
                                                     const float* __restrict__ b,
                                                     const float* __restrict__ c,
                                                     __hip_bfloat16* __restrict__ oa,
                                                     __hip_bfloat16* __restrict__ ob,
                                                     __hip_bfloat16* __restrict__ oc,
                                                     int na4, int nb4, int nc4) {
  const int ntot = na4 + nb4 + nc4;
  for (int i = blockIdx.x * 256 + threadIdx.x; i < ntot; i += gridDim.x * 256) {
    int j = i;
    const float* in; __hip_bfloat16* out;
    if (j < na4) { in = a; out = oa; }
    else if (j < na4 + nb4) { in = b; out = ob; j -= na4; }
    else { in = c; out = oc; j -= na4 + nb4; }
    float4 v = reinterpret_cast<const float4*>(in)[j];
    __hip_bfloat16 b0 = __float2bfloat16(v.x);
    __hip_bfloat16 b1 = __float2bfloat16(v.y);
    __hip_bfloat16 b2 = __float2bfloat16(v.z);
    __hip_bfloat16 b3 = __float2bfloat16(v.w);
    ushort4 u;
    u.x = *reinterpret_cast<unsigned short*>(&b0);
    u.y = *reinterpret_cast<unsigned short*>(&b1);
    u.z = *reinterpret_cast<unsigned short*>(&b2);
    u.w = *reinterpret_cast<unsigned short*>(&b3);
    reinterpret_cast<ushort4*>(out)[j] = u;
  }
}

// ---------------- GEMM 256^2: C[M,N] = A[M,K] * B[N,K]^T, bf16 out ---------
// 8 waves (2M x 4N), per-wave 128x64 out. 2-K-tile LDS dbuf (128 KB).
// Counted vmcnt (prefetch dist 2, entry wait vmcnt(8), raw s_barrier).
// T2 row-XOR swizzle on 16B slots (inverse-swz global source + swz ds_read).
__global__ __launch_bounds__(512, 1) void gemm_bt256(const __hip_bfloat16* __restrict__ A,
                                                     const __hip_bfloat16* __restrict__ B,
                                                     __hip_bfloat16* __restrict__ C,
                                                     int M, int N, int K) {
  __shared__ __hip_bfloat16 As[2][256 * 64];
  __shared__ __hip_bfloat16 Bs[2][256 * 64];
  const int tid = threadIdx.x;
  const int lane = tid & 63;
  const int wid = tid >> 6;
  const int l15 = lane & 15, l4 = lane >> 4;
  const int wr = wid >> 2;
  const int wc = wid & 3;
  const int m0 = blockIdx.x * 256, n0 = blockIdx.y * 256;
  const int NT = K >> 6;
  f32x4 acc[8][4] = {};

#define STAGE256(buf, kt)                                                            \
  do {                                                                               \
    _Pragma("unroll")                                                                \
    for (int i_ = 0; i_ < 4; ++i_) {                                                 \
      const int slot_ = i_ * 512 + tid;                                              \
      const int row_ = slot_ >> 3, c8_ = slot_ & 7;                                  \
      const int gc_ = (c8_ ^ (row_ & 7)) * 8;                                        \
      __builtin_amdgcn_global_load_lds(                                              \
          GLB_AS(A + (size_t)(m0 + row_) * K + (kt) + gc_),                          \
          LDS_AS((char*)As[buf] + slot_ * 16), 16, 0, 0);                            \
      __builtin_amdgcn_global_load_lds(                                              \
          GLB_AS(B + (size_t)(n0 + row_) * K + (kt) + gc_),                          \
          LDS_AS((char*)Bs[buf] + slot_ * 16), 16, 0, 0);                            \
    }                                                                                \
  } while (0)

  STAGE256(0, 0);
  if (NT > 1) STAGE256(1, 64);

  for (int t = 0; t < NT; ++t) {
    const int cur = t & 1;
    if (t < NT - 1) asm volatile("s_waitcnt vmcnt(8)" ::: "memory");
    else            asm volatile("s_waitcnt vmcnt(0)" ::: "memory");
    __builtin_amdgcn_sched_barrier(0);
    __builtin_amdgcn_s_barrier();
    asm volatile("" ::: "memory");

#pragma unroll
    for (int q = 0; q < 4; ++q) {
      const int mbase = wr * 128 + (q & 1) * 64;
      const int nbase = wc * 64 + (q >> 1) * 32;
      bf16x8 af[4][2], bfr[2][2];
#pragma unroll
      for (int mi = 0; mi < 4; ++mi)
#pragma unroll
        for (int kk = 0; kk < 2; ++kk) {
          const int r = mbase + mi * 16 + l15;
          af[mi][kk] = *reinterpret_cast<const bf16x8*>(
              &As[cur][r * 64 + (((kk * 4 + l4) ^ (r & 7)) * 8)]);
        }
#pragma unroll
      for (int nj = 0; nj < 2; ++nj)
#pragma unroll
        for (int kk = 0; kk < 2; ++kk) {
          const int r = nbase + nj * 16 + l15;
          bfr[nj][kk] = *reinterpret_cast<const bf16x8*>(
              &Bs[cur][r * 64 + (((kk * 4 + l4) ^ (r & 7)) * 8)]);
        }
      __builtin_amdgcn_s_setprio(1);
#pragma unroll
      for (int mi = 0; mi < 4; ++mi)
#pragma unroll
        for (int nj = 0; nj < 2; ++nj) {
          acc[(q & 1) * 4 + mi][(q >> 1) * 2 + nj] = __builtin_amdgcn_mfma_f32_16x16x32_bf16(
              af[mi][0], bfr[nj][0], acc[(q & 1) * 4 + mi][(q >> 1) * 2 + nj], 0, 0, 0);
          acc[(q & 1) * 4 + mi][(q >> 1) * 2 + nj] = __builtin_amdgcn_mfma_f32_16x16x32_bf16(
              af[mi][1], bfr[nj][1], acc[(q & 1) * 4 + mi][(q >> 1) * 2 + nj], 0, 0, 0);
        }
      __builtin_amdgcn_s_setprio(0);
    }
    // rule-18 fix: drain LDS reads and pin ALL ops (incl. register-only MFMA)
    // before signaling the barrier; otherwise a wave can pass the barrier
    // with ds_reads pending while another wave restages this buffer.
    asm volatile("s_waitcnt lgkmcnt(0)" ::: "memory");
    __builtin_amdgcn_sched_barrier(0);
    __builtin_amdgcn_s_barrier();
    asm volatile("" ::: "memory");
    if (t + 2 < NT) STAGE256(cur, (t + 2) << 6);
  }
#undef STAGE256

#pragma unroll
  for (int mi = 0; mi < 8; ++mi)
#pragma unroll
    for (int ni = 0; ni < 4; ++ni)
#pragma unroll
      for (int j = 0; j < 4; ++j) {
        const int m = m0 + wr * 128 + mi * 16 + l4 * 4 + j;
        const int n = n0 + wc * 64 + ni * 16 + l15;
        C[(size_t)m * N + n] = __float2bfloat16(acc[mi][ni][j]);
      }
}

// ------------- GEMM 256x128: C[M,N] = A[M,K]*B[N,K]^T, f32 out -------------
// 8 waves (4M x 2N), per-wave 64x64. Counted vmcnt: per-thread loads/stage
// L = 4(A)+2(B) = 6 -> steady-state entry wait vmcnt(6); prefetch dist 2;
// raw s_barrier; T2 both-sides swizzle. Same rule-18 drain before barrier2.
__global__ __launch_bounds__(512, 1) void gemm_bt256x128f(const __hip_bfloat16* __restrict__ A,
                                                          const __hip_bfloat16* __restrict__ B,
                                                          float* __restrict__ C,
                                                          int M, int N, int K) {
  __shared__ __hip_bfloat16 As[2][256 * 64];   // 64 KB
  __shared__ __hip_bfloat16 Bs[2][128 * 64];   // 32 KB
  const int tid = threadIdx.x;
  const int lane = tid & 63;
  const int wid = tid >> 6;
  const int l15 = lane & 15, l4 = lane >> 4;
  const int wr = (wid >> 1) * 64;
  const int wc = (wid & 1) * 64;
  const int m0 = blockIdx.x * 256, n0 = blockIdx.y * 128;
  const int NT = K >> 6;
  f32x4 acc[4][4] = {};

#define STAGE2(buf, kt)                                                              \
  do {                                                                               \
    _Pragma("unroll")                                                                \
    for (int i_ = 0; i_ < 4; ++i_) {                                                 \
      const int slot_ = i_ * 512 + tid;                                              \
      const int row_ = slot_ >> 3, c8_ = slot_ & 7;                                  \
      const int gc_ = (c8_ ^ (row_ & 7)) * 8;                                        \
      __builtin_amdgcn_global_load_lds(                                              \
          GLB_AS(A + (size_t)(m0 + row_) * K + (kt) + gc_),                          \
          LDS_AS((char*)As[buf] + slot_ * 16), 16, 0, 0);                            \
    }                                                                                \
    _Pragma("unroll")                                                                \
    for (int i_ = 0; i_ < 2; ++i_) {                                                 \
      const int slot_ = i_ * 512 + tid;                                              \
      const int row_ = slot_ >> 3, c8_ = slot_ & 7;                                  \
      const int gc_ = (c8_ ^ (row_ & 7)) * 8;                                        \
      __builtin_amdgcn_global_load_lds(                                              \
          GLB_AS(B + (size_t)(n0 + row_) * K + (kt) + gc_),                          \
          LDS_AS((char*)Bs[buf] + slot_ * 16), 16, 0, 0);                            \
    }                                                                                \
  } while (0)

  STAGE2(0, 0);
  if (NT > 1) STAGE2(1, 64);

  for (int t = 0; t < NT; ++t) {
    const int cur = t & 1;
    if (t < NT - 1) asm volatile("s_waitcnt vmcnt(6)" ::: "memory");
    else            asm volatile("s_waitcnt vmcnt(0)" ::: "memory");
    __builtin_amdgcn_sched_barrier(0);
    __builtin_amdgcn_s_barrier();
    asm volatile("" ::: "memory");

#pragma unroll
    for (int kk = 0; kk < 2; ++kk) {
      bf16x8 af[4], bfr[4];
#pragma unroll
      for (int mi = 0; mi < 4; ++mi) {
        const int r = wr + mi * 16 + l15;
        af[mi] = *reinterpret_cast<const bf16x8*>(
            &As[cur][r * 64 + (((kk * 4 + l4) ^ (r & 7)) * 8)]);
      }
#pragma unroll
      for (int ni = 0; ni < 4; ++ni) {
        const int r = wc + ni * 16 + l15;
        bfr[ni] = *reinterpret_cast<const bf16x8*>(
            &Bs[cur][r * 64 + (((kk * 4 + l4) ^ (r & 7)) * 8)]);
      }
      __builtin_amdgcn_s_setprio(1);
#pragma unroll
      for (int mi = 0; mi < 4; ++mi)
#pragma unroll
        for (int ni = 0; ni < 4; ++ni)
          acc[mi][ni] = __builtin_amdgcn_mfma_f32_16x16x32_bf16(af[mi], bfr[ni], acc[mi][ni], 0, 0, 0);
      __builtin_amdgcn_s_setprio(0);
    }
    // rule-18 fix: drain LDS reads before signaling barrier2 (see gemm_bt256).
    asm volatile("s_waitcnt lgkmcnt(0)" ::: "memory");
    __builtin_amdgcn_sched_barrier(0);
    __builtin_amdgcn_s_barrier();
    asm volatile("" ::: "memory");
    if (t + 2 < NT) STAGE2(cur, (t + 2) << 6);
  }
#undef STAGE2

#pragma unroll
  for (int mi = 0; mi < 4; ++mi)
#pragma unroll
    for (int ni = 0; ni < 4; ++ni)
#pragma unroll
      for (int j = 0; j < 4; ++j) {
        const int m = m0 + wr + mi * 16 + l4 * 4 + j;
        const int n = n0 + wc + ni * 16 + l15;
        C[(size_t)m * N + n] = acc[mi][ni][j];
      }
}

// --------------------------- causal flash attn -----------------------------
// R6 config (best measured: 119 us over 6 structural variants). 512 threads =
// 8 waves; waves 0-3 own 256-row q-tile x, waves 4-7 own 7-x (uniform
// per-SIMD work); 4 Q-frags/wave; grid 256 = 1 block/CU.
// __launch_bounds__(512,2) -> 128-VGPR cap, no spill. Uses __syncthreads()
// (full drain) -> no rule-18 hazard here.
__global__ __launch_bounds__(512, 2) void attn_causal(const __hip_bfloat16* __restrict__ qkv,
                                                      __hip_bfloat16* __restrict__ o) {
  constexpr int T = 2048, F = 3072, C = 1024;
  __shared__ __hip_bfloat16 Ks[2][64 * 72];
  __shared__ __hip_bfloat16 Vts[2][64 * 72];
  __shared__ __hip_bfloat16 Ps[8][16 * 72];
  const int tid = threadIdx.x;
  const int wid = tid >> 6, lane = tid & 63;
  const int l15 = lane & 15, l4 = lane >> 4;
  const int x = blockIdx.x, h = blockIdx.y, b = blockIdx.z;
  const int qt = (wid < 4) ? x : (7 - x);
  const int nt = 4 * (7 - x) + 4;
  const int tmax = 4 * qt + (wid & 3);
  const int hoff = h * 64;
  const __hip_bfloat16* base = qkv + (size_t)b * T * F;
  const int Q0 = qt * 256 + (wid & 3) * 64;

  constexpr float SC = 0.125f * 1.44269504088896f;

  bf16x8 aq[4][2];
#pragma unroll
  for (int f = 0; f < 4; ++f)
#pragma unroll
    for (int kk = 0; kk < 2; ++kk) {
      bf16x8 q = *reinterpret_cast<const bf16x8*>(base + (size_t)(Q0 + f * 16 + l15) * F + hoff + kk * 32 + l4 * 8);
#pragma unroll
      for (int e = 0; e < 8; ++e) {
        const unsigned short raw = (unsigned short)q[e];
        const float fv = __uint_as_float((unsigned)raw << 16) * SC;
        __hip_bfloat16 qs = __float2bfloat16(fv);
        q[e] = *reinterpret_cast<short*>(&qs);
      }
      aq[f][kk] = q;
    }

  f32x4 acc[4][4] = {};
  float mrun[4], lrun[4];
#pragma unroll
  for (int f = 0; f < 4; ++f) { mrun[f] = -1e30f; lrun[f] = 0.f; }

  const int sV = tid;
  const int sK = tid - 256;
  bf16x8 sreg0, sreg1;
  if (wid < 4) {
    const size_t vr = (size_t)(2 * (sV >> 3)) * F + hoff + 2 * C + (sV & 7) * 8;
    sreg0 = *reinterpret_cast<const bf16x8*>(base + vr);
    sreg1 = *reinterpret_cast<const bf16x8*>(base + vr + F);
  } else {
    sreg0 = *reinterpret_cast<const bf16x8*>(base + (size_t)(sK >> 3) * F + hoff + C + (sK & 7) * 8);
    sreg1 = *reinterpret_cast<const bf16x8*>(base + (size_t)(32 + (sK >> 3)) * F + hoff + C + (sK & 7) * 8);
  }

  for (int t = 0; t < nt; ++t) {
    const int cur = t & 1;
    if (wid < 4) {
      const unsigned short* a0 = reinterpret_cast<const unsigned short*>(&sreg0);
      const unsigned short* a1 = reinterpret_cast<const unsigned short*>(&sreg1);
      const int c8 = sV & 7, r2 = sV >> 3;
      unsigned pk[8], tw[8], pkr[8];
#pragma unroll
      for (int j = 0; j < 8; ++j) pk[j] = (unsigned)a0[j] | ((unsigned)a1[j] << 16);
#pragma unroll
      for (int j = 0; j < 8; ++j) tw[j] = (c8 & 4) ? pk[(j + 4) & 7] : pk[j];
#pragma unroll
      for (int j = 0; j < 8; ++j) pkr[j] = (c8 & 2) ? tw[(j + 2) & 7] : tw[j];
#pragma unroll
      for (int j = 0; j < 8; ++j) tw[j] = (c8 & 1) ? pkr[(j + 1) & 7] : pkr[j];
#pragma unroll
      for (int jj = 0; jj < 8; ++jj) {
        const int d = c8 * 8 + ((jj + c8) & 7);
        *reinterpret_cast<unsigned*>(&Vts[cur][d * 72 + 2 * r2]) = tw[jj];
      }
    } else {
      *reinterpret_cast<bf16x8*>(&Ks[cur][(sK >> 3) * 72 + (sK & 7) * 8]) = sreg0;
      *reinterpret_cast<bf16x8*>(&Ks[cur][(32 + (sK >> 3)) * 72 + (sK & 7) * 8]) = sreg1;
    }
    __syncthreads();
    if (t + 1 < nt) {
      const int kn = (t + 1) * 64;
      if (wid < 4) {
        const size_t vr = (size_t)(kn + 2 * (sV >> 3)) * F + hoff + 2 * C + (sV & 7) * 8;
        sreg0 = *reinterpret_cast<const bf16x8*>(base + vr);
        sreg1 = *reinterpret_cast<const bf16x8*>(base + vr + F);
      } else {
        sreg0 = *reinterpret_cast<const bf16x8*>(base + (size_t)(kn + (sK >> 3)) * F + hoff + C + (sK & 7) * 8);
        sreg1 = *reinterpret_cast<const bf16x8*>(base + (size_t)(kn + 32 + (sK >> 3)) * F + hoff + C + (sK & 7) * 8);
      }
    }
    if (t > tmax) continue;
    const bool diag = (t == tmax);

    bf16x8 kf[4][2], vf[4][2];
#pragma unroll
    for (int kt = 0; kt < 4; ++kt)
#pragma unroll
      for (int kk = 0; kk < 2; ++kk)
        kf[kt][kk] = *reinterpret_cast<const bf16x8*>(&Ks[cur][(kt * 16 + l15) * 72 + kk * 32 + l4 * 8]);
#pragma unroll
    for (int di = 0; di < 4; ++di)
#pragma unroll
      for (int kk = 0; kk < 2; ++kk)
        vf[di][kk] = *reinterpret_cast<const bf16x8*>(&Vts[cur][(di * 16 + l15) * 72 + kk * 32 + l4 * 8]);

    __hip_bfloat16* pw = Ps[wid];
#pragma unroll
    for (int f = 0; f < 4; ++f) {
      f32x4 s[4];
#pragma unroll
      for (int kt = 0; kt < 4; ++kt) {
        f32x4 z = {};
        z = __builtin_amdgcn_mfma_f32_16x16x32_bf16(kf[kt][0], aq[f][0], z, 0, 0, 0);
        z = __builtin_amdgcn_mfma_f32_16x16x32_bf16(kf[kt][1], aq[f][1], z, 0, 0, 0);
        s[kt] = z;
      }
      if (diag) {
        const int ql = f * 16 + l15;
#pragma unroll
        for (int kt = 0; kt < 4; ++kt)
#pragma unroll
          for (int j = 0; j < 4; ++j) {
            const int kvl = kt * 16 + l4 * 4 + j;
            s[kt][j] = (kvl <= ql) ? s[kt][j] : -1e30f;
          }
      }

      float t0 = fmaxf(fmaxf(s[0][0], s[0][1]), s[0][2]);
      float t1 = fmaxf(fmaxf(s[0][3], s[1][0]), s[1][1]);
      float t2 = fmaxf(fmaxf(s[1][2], s[1][3]), s[2][0]);
      float t3 = fmaxf(fmaxf(s[2][1], s[2][2]), s[2][3]);
      float t4 = fmaxf(fmaxf(s[3][0], s[3][1]), s[3][2]);
      float mt = fmaxf(fmaxf(fmaxf(t0, t1), fmaxf(t2, t3)), fmaxf(t4, s[3][3]));
      mt = fmaxf(mt, __shfl_xor(mt, 16, 64));
      mt = fmaxf(mt, __shfl_xor(mt, 32, 64));
      const bool defer = __all(mt <= mrun[f] + 8.f);
      const float mnew = defer ? mrun[f] : fmaxf(mrun[f], mt);
      float rs = 0.f;
#pragma unroll
      for (int kt = 0; kt < 4; ++kt) {
        float p0 = exp2f(s[kt][0] - mnew), p1 = exp2f(s[kt][1] - mnew);
        float p2 = exp2f(s[kt][2] - mnew), p3 = exp2f(s[kt][3] - mnew);
        s[kt][0] = p0; s[kt][1] = p1; s[kt][2] = p2; s[kt][3] = p3;
        rs += (p0 + p1) + (p2 + p3);
      }
      rs += __shfl_xor(rs, 16, 64);
      rs += __shfl_xor(rs, 32, 64);
      if (defer) {
        lrun[f] += rs;
      } else {
        const float sco = exp2f(mrun[f] - mnew);
        lrun[f] = lrun[f] * sco + rs;
        mrun[f] = mnew;
#pragma unroll
        for (int di = 0; di < 4; ++di) acc[f][di] *= sco;
      }

#pragma unroll
      for (int kt = 0; kt < 4; ++kt) {
        unsigned w0, w1;
        asm("v_cvt_pk_bf16_f32 %0, %1, %2" : "=v"(w0) : "v"(s[kt][0]), "v"(s[kt][1]));
        asm("v_cvt_pk_bf16_f32 %0, %1, %2" : "=v"(w1) : "v"(s[kt][2]), "v"(s[kt][3]));
        unsigned long long dw = (unsigned long long)w0 | ((unsigned long long)w1 << 32);
        *reinterpret_cast<unsigned long long*>(&pw[l15 * 72 + kt * 16 + l4 * 4]) = dw;
      }
      asm volatile("s_waitcnt lgkmcnt(0)" ::: "memory");
      __builtin_amdgcn_sched_barrier(0);
      bf16x8 pa0 = *reinterpret_cast<const bf16x8*>(pw + l15 * 72 + l4 * 8);
      bf16x8 pa1 = *reinterpret_cast<const bf16x8*>(pw + l15 * 72 + 32 + l4 * 8);

#pragma unroll
      for (int di = 0; di < 4; ++di) {
        acc[f][di] = __builtin_amdgcn_mfma_f32_16x16x32_bf16(vf[di][0], pa0, acc[f][di], 0, 0, 0);
        acc[f][di] = __builtin_amdgcn_mfma_f32_16x16x32_bf16(vf[di][1], pa1, acc[f][di], 0, 0, 0);
      }
    }
  }

#pragma unroll
  for (int f = 0; f < 4; ++f) {
    const float inv = 1.0f / lrun[f];
    __hip_bfloat16* op = o + (size_t)((size_t)b * T + Q0 + f * 16 + l15) * C + hoff;
#pragma unroll
    for (int di = 0; di < 4; ++di) {
      ushort4 u;
      __hip_bfloat16 e0 = __float2bfloat16(acc[f][di][0] * inv);
      __hip_bfloat16 e1 = __float2bfloat16(acc[f][di][1] * inv);
      __hip_bfloat16 e2 = __float2bfloat16(acc[f][di][2] * inv);
      __hip_bfloat16 e3 = __float2bfloat16(acc[f][di][3] * inv);
      u.x = *reinterpret_cast<unsigned short*>(&e0);
      u.y = *reinterpret_cast<unsigned short*>(&e1);
      u.z = *reinterpret_cast<unsigned short*>(&e2);
      u.w = *reinterpret_cast<unsigned short*>(&e3);
      *reinterpret_cast<ushort4*>(op + di * 16 + l4 * 4) = u;
    }
  }
}

// ------------------------------- launcher ----------------------------------
extern "C" void kernel_launch(void* const* d_in, const int* in_sizes, int n_in,
                              void* d_out, int out_size, void* d_ws, size_t ws_size,
                              hipStream_t stream) {
  const float* x = (const float*)d_in[0];
  const float* w_qkv = (const float*)d_in[1];
  const float* w_out = (const float*)d_in[2];
  float* out = (float*)d_out;

  constexpr int B = 4, T = 2048, C = 1024, F = 3 * C;
  constexpr int M = B * T;

  __hip_bfloat16* xb = (__hip_bfloat16*)d_ws;            // M*C
  __hip_bfloat16* wqkvb = xb + (size_t)M * C;            // F*C
  __hip_bfloat16* woutb = wqkvb + (size_t)F * C;         // C*C
  __hip_bfloat16* qkvb = woutb + (size_t)C * C;          // M*F
  __hip_bfloat16* attnb = qkvb + (size_t)M * F;          // M*C

  constexpr int na4 = M * C / 4, nb4 = F * C / 4, nc4 = C * C / 4;
  cvt3_f32_bf16<<<2048, 256, 0, stream>>>(x, w_qkv, w_out, xb, wqkvb, woutb, na4, nb4, nc4);

  gemm_bt256<<<dim3(M / 256, F / 256), 512, 0, stream>>>(xb, wqkvb, qkvb, M, F, C);

  attn_causal<<<dim3(4, 16, B), 512, 0, stream>>>(qkvb, attnb);

  gemm_bt256x128f<<<dim3(M / 256, C / 128), 512, 0, stream>>>(attnb, woutb, out, M, C, C);
}

// Round 17
// 209.421 us; speedup vs baseline: 1.2224x; 1.0544x over previous
//
#include <hip/hip_runtime.h>
#include <hip/hip_bf16.h>
#include <type_traits>

// ---------------------------------------------------------------------------
// CausalSelfAttention: x[4,2048,1024] f32, w_qkv[3072,1024], w_out[1024,1024]
// Pipeline: cvt(bf16) -> GEMM qkv (256x192 counted-vmcnt; 512 blocks = two
// FULL dispatch waves, no tail) -> causal flash attn (16x16, R6 config)
// -> GEMM out (256x128 counted-vmcnt, f32).
// Rule-18 race fix (R15/R16): lgkmcnt(0)+sched_barrier(0) before barrier2.
// ---------------------------------------------------------------------------

typedef __attribute__((ext_vector_type(8))) short bf16x8;
typedef __attribute__((ext_vector_type(4))) float f32x4;

#define LDS_AS(p) ((__attribute__((address_space(3))) void*)(p))
#define GLB_AS(p) ((const __attribute__((address_space(1))) void*)(p))

// ------------------- fp32 -> bf16 (all three inputs, one launch) -----------
__global__ __launch_bounds__(256) void cvt3_f32_bf16(const float* __restrict__ a,
                                                     const float* __restrict__ b,
                                                     const float* __restrict__ c,
                                                     __hip_bfloat16* __restrict__ oa,
                                                     __hip_bfloat16* __restrict__ ob,
                                                     __hip_bfloat16* __restrict__ oc,
                                                     int na4, int nb4, int nc4) {
  const int ntot = na4 + nb4 + nc4;
  for (int i = blockIdx.x * 256 + threadIdx.x; i < ntot; i += gridDim.x * 256) {
    int j = i;
    const float* in; __hip_bfloat16* out;
    if (j < na4) { in = a; out = oa; }
    else if (j < na4 + nb4) { in = b; out = ob; j -= na4; }
    else { in = c; out = oc; j -= na4 + nb4; }
    float4 v = reinterpret_cast<const float4*>(in)[j];
    __hip_bfloat16 b0 = __float2bfloat16(v.x);
    __hip_bfloat16 b1 = __float2bfloat16(v.y);
    __hip_bfloat16 b2 = __float2bfloat16(v.z);
    __hip_bfloat16 b3 = __float2bfloat16(v.w);
    ushort4 u;
    u.x = *reinterpret_cast<unsigned short*>(&b0);
    u.y = *reinterpret_cast<unsigned short*>(&b1);
    u.z = *reinterpret_cast<unsigned short*>(&b2);
    u.w = *reinterpret_cast<unsigned short*>(&b3);
    reinterpret_cast<ushort4*>(out)[j] = u;
  }
}

// ------------- GEMM 256x192: C[M,N] = A[M,K]*B[N,K]^T, bf16 out ------------
// 8 waves (2M x 4N), per-wave 128x48 out (acc[8][3]). 2-K-tile LDS dbuf
// (112 KB). Counted vmcnt: L = 4(A)+3(B) = 7 loads/stage -> steady entry
// wait vmcnt(7); prefetch dist 2; raw s_barrier; T2 both-sides swizzle;
// rule-18 drain before barrier2. Grid (M/256)x(N/192) = 32x16 = 512 blocks
// = exactly two full dispatch waves at 1 block/CU (no tail; the old 256^2
// tile gave 384 blocks -> 25% tail idle).
__global__ __launch_bounds__(512, 1) void gemm_bt256x192(const __hip_bfloat16* __restrict__ A,
                                                         const __hip_bfloat16* __restrict__ B,
                                                         __hip_bfloat16* __restrict__ C,
                                                         int M, int N, int K) {
  __shared__ __hip_bfloat16 As[2][256 * 64];   // 64 KB
  __shared__ __hip_bfloat16 Bs[2][192 * 64];   // 48 KB
  const int tid = threadIdx.x;
  const int lane = tid & 63;
  const int wid = tid >> 6;
  const int l15 = lane & 15, l4 = lane >> 4;
  const int wrH = wid >> 2;                    // 0..1 (M half)
  const int wc = wid & 3;                      // 0..3 (N quarter, 48 cols)
  const int m0 = blockIdx.x * 256, n0 = blockIdx.y * 192;
  const int NT = K >> 6;
  f32x4 acc[8][3] = {};

#define STAGEQ(buf, kt)                                                              \
  do {                                                                               \
    _Pragma("unroll")                                                                \
    for (int i_ = 0; i_ < 4; ++i_) {                                                 \
      const int slot_ = i_ * 512 + tid;                                              \
      const int row_ = slot_ >> 3, c8_ = slot_ & 7;                                  \
      const int gc_ = (c8_ ^ (row_ & 7)) * 8;                                        \
      __builtin_amdgcn_global_load_lds(                                              \
          GLB_AS(A + (size_t)(m0 + row_) * K + (kt) + gc_),                          \
          LDS_AS((char*)As[buf] + slot_ * 16), 16, 0, 0);                            \
    }                                                                                \
    _Pragma("unroll")                                                                \
    for (int i_ = 0; i_ < 3; ++i_) {                                                 \
      const int slot_ = i_ * 512 + tid;                                              \
      const int row_ = slot_ >> 3, c8_ = slot_ & 7;                                  \
      const int gc_ = (c8_ ^ (row_ & 7)) * 8;                                        \
      __builtin_amdgcn_global_load_lds(                                              \
          GLB_AS(B + (size_t)(n0 + row_) * K + (kt) + gc_),                          \
          LDS_AS((char*)Bs[buf] + slot_ * 16), 16, 0, 0);                            \
    }                                                                                \
  } while (0)

  STAGEQ(0, 0);
  if (NT > 1) STAGEQ(1, 64);

  for (int t = 0; t < NT; ++t) {
    const int cur = t & 1;
    if (t < NT - 1) asm volatile("s_waitcnt vmcnt(7)" ::: "memory");
    else            asm volatile("s_waitcnt vmcnt(0)" ::: "memory");
    __builtin_amdgcn_sched_barrier(0);
    __builtin_amdgcn_s_barrier();
    asm volatile("" ::: "memory");

    // B-frags shared by both m-phases: hoist once
    bf16x8 bfr[3][2];
#pragma unroll
    for (int nj = 0; nj < 3; ++nj)
#pragma unroll
      for (int kk = 0; kk < 2; ++kk) {
        const int r = wc * 48 + nj * 16 + l15;
        bfr[nj][kk] = *reinterpret_cast<const bf16x8*>(
            &Bs[cur][r * 64 + (((kk * 4 + l4) ^ (r & 7)) * 8)]);
      }
#pragma unroll
    for (int q = 0; q < 2; ++q) {
      const int mbase = wrH * 128 + q * 64;
      bf16x8 af[4][2];
#pragma unroll
      for (int mi = 0; mi < 4; ++mi)
#pragma unroll
        for (int kk = 0; kk < 2; ++kk) {
          const int r = mbase + mi * 16 + l15;
          af[mi][kk] = *reinterpret_cast<const bf16x8*>(
              &As[cur][r * 64 + (((kk * 4 + l4) ^ (r & 7)) * 8)]);
        }
      __builtin_amdgcn_s_setprio(1);
#pragma unroll
      for (int mi = 0; mi < 4; ++mi)
#pragma unroll
        for (int nj = 0; nj < 3; ++nj) {
          acc[q * 4 + mi][nj] = __builtin_amdgcn_mfma_f32_16x16x32_bf16(
              af[mi][0], bfr[nj][0], acc[q * 4 + mi][nj], 0, 0, 0);
          acc[q * 4 + mi][nj] = __builtin_amdgcn_mfma_f32_16x16x32_bf16(
              af[mi][1], bfr[nj][1], acc[q * 4 + mi][nj], 0, 0, 0);
        }
      __builtin_amdgcn_s_setprio(0);
    }
    // rule-18 fix: drain LDS reads and pin ALL ops before signaling barrier2.
    asm volatile("s_waitcnt lgkmcnt(0)" ::: "memory");
    __builtin_amdgcn_sched_barrier(0);
    __builtin_amdgcn_s_barrier();
    asm volatile("" ::: "memory");
    if (t + 2 < NT) STAGEQ(cur, (t + 2) << 6);
  }
#undef STAGEQ

#pragma unroll
  for (int a = 0; a < 8; ++a)
#pragma unroll
    for (int nj = 0; nj < 3; ++nj)
#pragma unroll
      for (int j = 0; j < 4; ++j) {
        const int m = m0 + wrH * 128 + (a >> 2) * 64 + (a & 3) * 16 + l4 * 4 + j;
        const int n = n0 + wc * 48 + nj * 16 + l15;
        C[(size_t)m * N + n] = __float2bfloat16(acc[a][nj][j]);
      }
}

// ------------- GEMM 256x128: C[M,N] = A[M,K]*B[N,K]^T, f32 out -------------
// 8 waves (4M x 2N), per-wave 64x64. Counted vmcnt: L = 4(A)+2(B) = 6 ->
// steady entry wait vmcnt(6); prefetch dist 2; raw s_barrier; T2 both-sides
// swizzle; rule-18 drain before barrier2. Grid = 256 blocks = 1 full wave.
__global__ __launch_bounds__(512, 1) void gemm_bt256x128f(const __hip_bfloat16* __restrict__ A,
                                                          const __hip_bfloat16* __restrict__ B,
                                                          float* __restrict__ C,
                                                          int M, int N, int K) {
  __shared__ __hip_bfloat16 As[2][256 * 64];   // 64 KB
  __shared__ __hip_bfloat16 Bs[2][128 * 64];   // 32 KB
  const int tid = threadIdx.x;
  const int lane = tid & 63;
  const int wid = tid >> 6;
  const int l15 = lane & 15, l4 = lane >> 4;
  const int wr = (wid >> 1) * 64;
  const int wc = (wid & 1) * 64;
  const int m0 = blockIdx.x * 256, n0 = blockIdx.y * 128;
  const int NT = K >> 6;
  f32x4 acc[4][4] = {};

#define STAGE2(buf, kt)                                                              \
  do {                                                                               \
    _Pragma("unroll")                                                                \
    for (int i_ = 0; i_ < 4; ++i_) {                                                 \
      const int slot_ = i_ * 512 + tid;                                              \
      const int row_ = slot_ >> 3, c8_ = slot_ & 7;                                  \
      const int gc_ = (c8_ ^ (row_ & 7)) * 8;                                        \
      __builtin_amdgcn_global_load_lds(                                              \
          GLB_AS(A + (size_t)(m0 + row_) * K + (kt) + gc_),                          \
          LDS_AS((char*)As[buf] + slot_ * 16), 16, 0, 0);                            \
    }                                                                                \
    _Pragma("unroll")                                                                \
    for (int i_ = 0; i_ < 2; ++i_) {                                                 \
      const int slot_ = i_ * 512 + tid;                                              \
      const int row_ = slot_ >> 3, c8_ = slot_ & 7;                                  \
      const int gc_ = (c8_ ^ (row_ & 7)) * 8;                                        \
      __builtin_amdgcn_global_load_lds(                                              \
          GLB_AS(B + (size_t)(n0 + row_) * K + (kt) + gc_),                          \
          LDS_AS((char*)Bs[buf] + slot_ * 16), 16, 0, 0);                            \
    }                                                                                \
  } while (0)

  STAGE2(0, 0);
  if (NT > 1) STAGE2(1, 64);

  for (int t = 0; t < NT; ++t) {
    const int cur = t & 1;
    if (t < NT - 1) asm volatile("s_waitcnt vmcnt(6)" ::: "memory");
    else            asm volatile("s_waitcnt vmcnt(0)" ::: "memory");
    __builtin_amdgcn_sched_barrier(0);
    __builtin_amdgcn_s_barrier();
    asm volatile("" ::: "memory");

#pragma unroll
    for (int kk = 0; kk < 2; ++kk) {
      bf16x8 af[4], bfr[4];
#pragma unroll
      for (int mi = 0; mi < 4; ++mi) {
        const int r = wr + mi * 16 + l15;
        af[mi] = *reinterpret_cast<const bf16x8*>(
            &As[cur][r * 64 + (((kk * 4 + l4) ^ (r & 7)) * 8)]);
      }
#pragma unroll
      for (int ni = 0; ni < 4; ++ni) {
        const int r = wc + ni * 16 + l15;
        bfr[ni] = *reinterpret_cast<const bf16x8*>(
            &Bs[cur][r * 64 + (((kk * 4 + l4) ^ (r & 7)) * 8)]);
      }
      __builtin_amdgcn_s_setprio(1);
#pragma unroll
      for (int mi = 0; mi < 4; ++mi)
#pragma unroll
        for (int ni = 0; ni < 4; ++ni)
          acc[mi][ni] = __builtin_amdgcn_mfma_f32_16x16x32_bf16(af[mi], bfr[ni], acc[mi][ni], 0, 0, 0);
      __builtin_amdgcn_s_setprio(0);
    }
    // rule-18 fix: drain LDS reads before signaling barrier2.
    asm volatile("s_waitcnt lgkmcnt(0)" ::: "memory");
    __builtin_amdgcn_sched_barrier(0);
    __builtin_amdgcn_s_barrier();
    asm volatile("" ::: "memory");
    if (t + 2 < NT) STAGE2(cur, (t + 2) << 6);
  }
#undef STAGE2

#pragma unroll
  for (int mi = 0; mi < 4; ++mi)
#pragma unroll
    for (int ni = 0; ni < 4; ++ni)
#pragma unroll
      for (int j = 0; j < 4; ++j) {
        const int m = m0 + wr + mi * 16 + l4 * 4 + j;
        const int n = n0 + wc + ni * 16 + l15;
        C[(size_t)m * N + n] = acc[mi][ni][j];
      }
}

// --------------------------- causal flash attn -----------------------------
// R6 config (best measured: 119 us over 6 structural variants). 512 threads =
// 8 waves; waves 0-3 own 256-row q-tile x, waves 4-7 own 7-x (uniform
// per-SIMD work); 4 Q-frags/wave; grid 256 = 1 block/CU.
// __launch_bounds__(512,2) -> 128-VGPR cap, no spill. Uses __syncthreads()
// (full drain) -> no rule-18 hazard here.
__global__ __launch_bounds__(512, 2) void attn_causal(const __hip_bfloat16* __restrict__ qkv,
                                                      __hip_bfloat16* __restrict__ o) {
  constexpr int T = 2048, F = 3072, C = 1024;
  __shared__ __hip_bfloat16 Ks[2][64 * 72];
  __shared__ __hip_bfloat16 Vts[2][64 * 72];
  __shared__ __hip_bfloat16 Ps[8][16 * 72];
  const int tid = threadIdx.x;
  const int wid = tid >> 6, lane = tid & 63;
  const int l15 = lane & 15, l4 = lane >> 4;
  const int x = blockIdx.x, h = blockIdx.y, b = blockIdx.z;
  const int qt = (wid < 4) ? x : (7 - x);
  const int nt = 4 * (7 - x) + 4;
  const int tmax = 4 * qt + (wid & 3);
  const int hoff = h * 64;
  const __hip_bfloat16* base = qkv + (size_t)b * T * F;
  const int Q0 = qt * 256 + (wid & 3) * 64;

  constexpr float SC = 0.125f * 1.44269504088896f;

  bf16x8 aq[4][2];
#pragma unroll
  for (int f = 0; f < 4; ++f)
#pragma unroll
    for (int kk = 0; kk < 2; ++kk) {
      bf16x8 q = *reinterpret_cast<const bf16x8*>(base + (size_t)(Q0 + f * 16 + l15) * F + hoff + kk * 32 + l4 * 8);
#pragma unroll
      for (int e = 0; e < 8; ++e) {
        const unsigned short raw = (unsigned short)q[e];
        const float fv = __uint_as_float((unsigned)raw << 16) * SC;
        __hip_bfloat16 qs = __float2bfloat16(fv);
        q[e] = *reinterpret_cast<short*>(&qs);
      }
      aq[f][kk] = q;
    }

  f32x4 acc[4][4] = {};
  float mrun[4], lrun[4];
#pragma unroll
  for (int f = 0; f < 4; ++f) { mrun[f] = -1e30f; lrun[f] = 0.f; }

  const int sV = tid;
  const int sK = tid - 256;
  bf16x8 sreg0, sreg1;
  if (wid < 4) {
    const size_t vr = (size_t)(2 * (sV >> 3)) * F + hoff + 2 * C + (sV & 7) * 8;
    sreg0 = *reinterpret_cast<const bf16x8*>(base + vr);
    sreg1 = *reinterpret_cast<const bf16x8*>(base + vr + F);
  } else {
    sreg0 = *reinterpret_cast<const bf16x8*>(base + (size_t)(sK >> 3) * F + hoff + C + (sK & 7) * 8);
    sreg1 = *reinterpret_cast<const bf16x8*>(base + (size_t)(32 + (sK >> 3)) * F + hoff + C + (sK & 7) * 8);
  }

  for (int t = 0; t < nt; ++t) {
    const int cur = t & 1;
    if (wid < 4) {
      const unsigned short* a0 = reinterpret_cast<const unsigned short*>(&sreg0);
      const unsigned short* a1 = reinterpret_cast<const unsigned short*>(&sreg1);
      const int c8 = sV & 7, r2 = sV >> 3;
      unsigned pk[8], tw[8], pkr[8];
#pragma unroll
      for (int j = 0; j < 8; ++j) pk[j] = (unsigned)a0[j] | ((unsigned)a1[j] << 16);
#pragma unroll
      for (int j = 0; j < 8; ++j) tw[j] = (c8 & 4) ? pk[(j + 4) & 7] : pk[j];
#pragma unroll
      for (int j = 0; j < 8; ++j) pkr[j] = (c8 & 2) ? tw[(j + 2) & 7] : tw[j];
#pragma unroll
      for (int j = 0; j < 8; ++j) tw[j] = (c8 & 1) ? pkr[(j + 1) & 7] : pkr[j];
#pragma unroll
      for (int jj = 0; jj < 8; ++jj) {
        const int d = c8 * 8 + ((jj + c8) & 7);
        *reinterpret_cast<unsigned*>(&Vts[cur][d * 72 + 2 * r2]) = tw[jj];
      }
    } else {
      *reinterpret_cast<bf16x8*>(&Ks[cur][(sK >> 3) * 72 + (sK & 7) * 8]) = sreg0;
      *reinterpret_cast<bf16x8*>(&Ks[cur][(32 + (sK >> 3)) * 72 + (sK & 7) * 8]) = sreg1;
    }
    __syncthreads();
    if (t + 1 < nt) {
      const int kn = (t + 1) * 64;
      if (wid < 4) {
        const size_t vr = (size_t)(kn + 2 * (sV >> 3)) * F + hoff + 2 * C + (sV & 7) * 8;
        sreg0 = *reinterpret_cast<const bf16x8*>(base + vr);
        sreg1 = *reinterpret_cast<const bf16x8*>(base + vr + F);
      } else {
        sreg0 = *reinterpret_cast<const bf16x8*>(base + (size_t)(kn + (sK >> 3)) * F + hoff + C + (sK & 7) * 8);
        sreg1 = *reinterpret_cast<const bf16x8*>(base + (size_t)(kn + 32 + (sK >> 3)) * F + hoff + C + (sK & 7) * 8);
      }
    }
    if (t > tmax) continue;
    const bool diag = (t == tmax);

    bf16x8 kf[4][2], vf[4][2];
#pragma unroll
    for (int kt = 0; kt < 4; ++kt)
#pragma unroll
      for (int kk = 0; kk < 2; ++kk)
        kf[kt][kk] = *reinterpret_cast<const bf16x8*>(&Ks[cur][(kt * 16 + l15) * 72 + kk * 32 + l4 * 8]);
#pragma unroll
    for (int di = 0; di < 4; ++di)
#pragma unroll
      for (int kk = 0; kk < 2; ++kk)
        vf[di][kk] = *reinterpret_cast<const bf16x8*>(&Vts[cur][(di * 16 + l15) * 72 + kk * 32 + l4 * 8]);

    __hip_bfloat16* pw = Ps[wid];
#pragma unroll
    for (int f = 0; f < 4; ++f) {
      f32x4 s[4];
#pragma unroll
      for (int kt = 0; kt < 4; ++kt) {
        f32x4 z = {};
        z = __builtin_amdgcn_mfma_f32_16x16x32_bf16(kf[kt][0], aq[f][0], z, 0, 0, 0);
        z = __builtin_amdgcn_mfma_f32_16x16x32_bf16(kf[kt][1], aq[f][1], z, 0, 0, 0);
        s[kt] = z;
      }
      if (diag) {
        const int ql = f * 16 + l15;
#pragma unroll
        for (int kt = 0; kt < 4; ++kt)
#pragma unroll
          for (int j = 0; j < 4; ++j) {
            const int kvl = kt * 16 + l4 * 4 + j;
            s[kt][j] = (kvl <= ql) ? s[kt][j] : -1e30f;
          }
      }

      float t0 = fmaxf(fmaxf(s[0][0], s[0][1]), s[0][2]);
      float t1 = fmaxf(fmaxf(s[0][3], s[1][0]), s[1][1]);
      float t2 = fmaxf(fmaxf(s[1][2], s[1][3]), s[2][0]);
      float t3 = fmaxf(fmaxf(s[2][1], s[2][2]), s[2][3]);
      float t4 = fmaxf(fmaxf(s[3][0], s[3][1]), s[3][2]);
      float mt = fmaxf(fmaxf(fmaxf(t0, t1), fmaxf(t2, t3)), fmaxf(t4, s[3][3]));
      mt = fmaxf(mt, __shfl_xor(mt, 16, 64));
      mt = fmaxf(mt, __shfl_xor(mt, 32, 64));
      const bool defer = __all(mt <= mrun[f] + 8.f);
      const float mnew = defer ? mrun[f] : fmaxf(mrun[f], mt);
      float rs = 0.f;
#pragma unroll
      for (int kt = 0; kt < 4; ++kt) {
        float p0 = exp2f(s[kt][0] - mnew), p1 = exp2f(s[kt][1] - mnew);
        float p2 = exp2f(s[kt][2] - mnew), p3 = exp2f(s[kt][3] - mnew);
        s[kt][0] = p0; s[kt][1] = p1; s[kt][2] = p2; s[kt][3] = p3;
        rs += (p0 + p1) + (p2 + p3);
      }
      rs += __shfl_xor(rs, 16, 64);
      rs += __shfl_xor(rs, 32, 64);
      if (defer) {
        lrun[f] += rs;
      } else {
        const float sco = exp2f(mrun[f] - mnew);
        lrun[f] = lrun[f] * sco + rs;
        mrun[f] = mnew;
#pragma unroll
        for (int di = 0; di < 4; ++di) acc[f][di] *= sco;
      }

#pragma unroll
      for (int kt = 0; kt < 4; ++kt) {
        unsigned w0, w1;
        asm("v_cvt_pk_bf16_f32 %0, %1, %2" : "=v"(w0) : "v"(s[kt][0]), "v"(s[kt][1]));
        asm("v_cvt_pk_bf16_f32 %0, %1, %2" : "=v"(w1) : "v"(s[kt][2]), "v"(s[kt][3]));
        unsigned long long dw = (unsigned long long)w0 | ((unsigned long long)w1 << 32);
        *reinterpret_cast<unsigned long long*>(&pw[l15 * 72 + kt * 16 + l4 * 4]) = dw;
      }
      asm volatile("s_waitcnt lgkmcnt(0)" ::: "memory");
      __builtin_amdgcn_sched_barrier(0);
      bf16x8 pa0 = *reinterpret_cast<const bf16x8*>(pw + l15 * 72 + l4 * 8);
      bf16x8 pa1 = *reinterpret_cast<const bf16x8*>(pw + l15 * 72 + 32 + l4 * 8);

#pragma unroll
      for (int di = 0; di < 4; ++di) {
        acc[f][di] = __builtin_amdgcn_mfma_f32_16x16x32_bf16(vf[di][0], pa0, acc[f][di], 0, 0, 0);
        acc[f][di] = __builtin_amdgcn_mfma_f32_16x16x32_bf16(vf[di][1], pa1, acc[f][di], 0, 0, 0);
      }
    }
  }

#pragma unroll
  for (int f = 0; f < 4; ++f) {
    const float inv = 1.0f / lrun[f];
    __hip_bfloat16* op = o + (size_t)((size_t)b * T + Q0 + f * 16 + l15) * C + hoff;
#pragma unroll
    for (int di = 0; di < 4; ++di) {
      ushort4 u;
      __hip_bfloat16 e0 = __float2bfloat16(acc[f][di][0] * inv);
      __hip_bfloat16 e1 = __float2bfloat16(acc[f][di][1] * inv);
      __hip_bfloat16 e2 = __float2bfloat16(acc[f][di][2] * inv);
      __hip_bfloat16 e3 = __float2bfloat16(acc[f][di][3] * inv);
      u.x = *reinterpret_cast<unsigned short*>(&e0);
      u.y = *reinterpret_cast<unsigned short*>(&e1);
      u.z = *reinterpret_cast<unsigned short*>(&e2);
      u.w = *reinterpret_cast<unsigned short*>(&e3);
      *reinterpret_cast<ushort4*>(op + di * 16 + l4 * 4) = u;
    }
  }
}

// ------------------------------- launcher ----------------------------------
extern "C" void kernel_launch(void* const* d_in, const int* in_sizes, int n_in,
                              void* d_out, int out_size, void* d_ws, size_t ws_size,
                              hipStream_t stream) {
  const float* x = (const float*)d_in[0];
  const float* w_qkv = (const float*)d_in[1];
  const float* w_out = (const float*)d_in[2];
  float* out = (float*)d_out;

  constexpr int B = 4, T = 2048, C = 1024, F = 3 * C;
  constexpr int M = B * T;

  __hip_bfloat16* xb = (__hip_bfloat16*)d_ws;            // M*C
  __hip_bfloat16* wqkvb = xb + (size_t)M * C;            // F*C
  __hip_bfloat16* woutb = wqkvb + (size_t)F * C;         // C*C
  __hip_bfloat16* qkvb = woutb + (size_t)C * C;          // M*F
  __hip_bfloat16* attnb = qkvb + (size_t)M * F;          // M*C

  constexpr int na4 = M * C / 4, nb4 = F * C / 4, nc4 = C * C / 4;
  cvt3_f32_bf16<<<2048, 256, 0, stream>>>(x, w_qkv, w_out, xb, wqkvb, woutb, na4, nb4, nc4);

  gemm_bt256x192<<<dim3(M / 256, F / 192), 512, 0, stream>>>(xb, wqkvb, qkvb, M, F, C);

  attn_causal<<<dim3(4, 16, B), 512, 0, stream>>>(qkvb, attnb);

  gemm_bt256x128f<<<dim3(M / 256, C / 128), 512, 0, stream>>>(attnb, woutb, out, M, C, C);
}

// Round 18
// 208.198 us; speedup vs baseline: 1.2296x; 1.0059x over previous
//
#include <hip/hip_runtime.h>
#include <hip/hip_bf16.h>
#include <type_traits>

// ---------------------------------------------------------------------------
// CausalSelfAttention: x[4,2048,1024] f32, w_qkv[3072,1024], w_out[1024,1024]
// Pipeline: cvt(bf16) -> GEMM qkv (256x192 counted-vmcnt; 512 blocks = two
// FULL dispatch waves, no tail) -> causal flash attn (16x16, R6 config,
// (512,1) reg budget) -> GEMM out (256x128 counted-vmcnt, f32).
// Rule-18 race fix (R15/R16) retained in BOTH GEMMs: lgkmcnt(0) +
// sched_barrier(0) before barrier2. Attn keeps only the lgkm memory fence
// (write->read ordering is memory-op ordering; no reg-only hoist hazard).
// ---------------------------------------------------------------------------

typedef __attribute__((ext_vector_type(8))) short bf16x8;
typedef __attribute__((ext_vector_type(4))) float f32x4;

#define LDS_AS(p) ((__attribute__((address_space(3))) void*)(p))
#define GLB_AS(p) ((const __attribute__((address_space(1))) void*)(p))

// ------------------- fp32 -> bf16 (all three inputs, one launch) -----------
__global__ __launch_bounds__(256) void cvt3_f32_bf16(const float* __restrict__ a,
                                                     const float* __restrict__ b,
                                                     const float* __restrict__ c,
                                                     __hip_bfloat16* __restrict__ oa,
                                                     __hip_bfloat16* __restrict__ ob,
                                                     __hip_bfloat16* __restrict__ oc,
                                                     int na4, int nb4, int nc4) {
  const int ntot = na4 + nb4 + nc4;
  for (int i = blockIdx.x * 256 + threadIdx.x; i < ntot; i += gridDim.x * 256) {
    int j = i;
    const float* in; __hip_bfloat16* out;
    if (j < na4) { in = a; out = oa; }
    else if (j < na4 + nb4) { in = b; out = ob; j -= na4; }
    else { in = c; out = oc; j -= na4 + nb4; }
    float4 v = reinterpret_cast<const float4*>(in)[j];
    __hip_bfloat16 b0 = __float2bfloat16(v.x);
    __hip_bfloat16 b1 = __float2bfloat16(v.y);
    __hip_bfloat16 b2 = __float2bfloat16(v.z);
    __hip_bfloat16 b3 = __float2bfloat16(v.w);
    ushort4 u;
    u.x = *reinterpret_cast<unsigned short*>(&b0);
    u.y = *reinterpret_cast<unsigned short*>(&b1);
    u.z = *reinterpret_cast<unsigned short*>(&b2);
    u.w = *reinterpret_cast<unsigned short*>(&b3);
    reinterpret_cast<ushort4*>(out)[j] = u;
  }
}

// ------------- GEMM 256x192: C[M,N] = A[M,K]*B[N,K]^T, bf16 out ------------
// 8 waves (2M x 4N), per-wave 128x48 out (acc[8][3]). 2-K-tile LDS dbuf
// (112 KB). Counted vmcnt: L = 4(A)+3(B) = 7 loads/stage -> steady entry
// wait vmcnt(7); prefetch dist 2; raw s_barrier; T2 both-sides swizzle;
// rule-18 drain before barrier2. Grid (M/256)x(N/192) = 32x16 = 512 blocks
// = exactly two full dispatch waves at 1 block/CU (no tail).
__global__ __launch_bounds__(512, 1) void gemm_bt256x192(const __hip_bfloat16* __restrict__ A,
                                                         const __hip_bfloat16* __restrict__ B,
                                                         __hip_bfloat16* __restrict__ C,
                                                         int M, int N, int K) {
  __shared__ __hip_bfloat16 As[2][256 * 64];   // 64 KB
  __shared__ __hip_bfloat16 Bs[2][192 * 64];   // 48 KB
  const int tid = threadIdx.x;
  const int lane = tid & 63;
  const int wid = tid >> 6;
  const int l15 = lane & 15, l4 = lane >> 4;
  const int wrH = wid >> 2;                    // 0..1 (M half)
  const int wc = wid & 3;                      // 0..3 (N quarter, 48 cols)
  const int m0 = blockIdx.x * 256, n0 = blockIdx.y * 192;
  const int NT = K >> 6;
  f32x4 acc[8][3] = {};

#define STAGEQ(buf, kt)                                                              \
  do {                                                                               \
    _Pragma("unroll")                                                                \
    for (int i_ = 0; i_ < 4; ++i_) {                                                 \
      const int slot_ = i_ * 512 + tid;                                              \
      const int row_ = slot_ >> 3, c8_ = slot_ & 7;                                  \
      const int gc_ = (c8_ ^ (row_ & 7)) * 8;                                        \
      __builtin_amdgcn_global_load_lds(                                              \
          GLB_AS(A + (size_t)(m0 + row_) * K + (kt) + gc_),                          \
          LDS_AS((char*)As[buf] + slot_ * 16), 16, 0, 0);                            \
    }                                                                                \
    _Pragma("unroll")                                                                \
    for (int i_ = 0; i_ < 3; ++i_) {                                                 \
      const int slot_ = i_ * 512 + tid;                                              \
      const int row_ = slot_ >> 3, c8_ = slot_ & 7;                                  \
      const int gc_ = (c8_ ^ (row_ & 7)) * 8;                                        \
      __builtin_amdgcn_global_load_lds(                                              \
          GLB_AS(B + (size_t)(n0 + row_) * K + (kt) + gc_),                          \
          LDS_AS((char*)Bs[buf] + slot_ * 16), 16, 0, 0);                            \
    }                                                                                \
  } while (0)

  STAGEQ(0, 0);
  if (NT > 1) STAGEQ(1, 64);

  for (int t = 0; t < NT; ++t) {
    const int cur = t & 1;
    if (t < NT - 1) asm volatile("s_waitcnt vmcnt(7)" ::: "memory");
    else            asm volatile("s_waitcnt vmcnt(0)" ::: "memory");
    __builtin_amdgcn_sched_barrier(0);
    __builtin_amdgcn_s_barrier();
    asm volatile("" ::: "memory");

    // B-frags shared by both m-phases: hoist once
    bf16x8 bfr[3][2];
#pragma unroll
    for (int nj = 0; nj < 3; ++nj)
#pragma unroll
      for (int kk = 0; kk < 2; ++kk) {
        const int r = wc * 48 + nj * 16 + l15;
        bfr[nj][kk] = *reinterpret_cast<const bf16x8*>(
            &Bs[cur][r * 64 + (((kk * 4 + l4) ^ (r & 7)) * 8)]);
      }
#pragma unroll
    for (int q = 0; q < 2; ++q) {
      const int mbase = wrH * 128 + q * 64;
      bf16x8 af[4][2];
#pragma unroll
      for (int mi = 0; mi < 4; ++mi)
#pragma unroll
        for (int kk = 0; kk < 2; ++kk) {
          const int r = mbase + mi * 16 + l15;
          af[mi][kk] = *reinterpret_cast<const bf16x8*>(
              &As[cur][r * 64 + (((kk * 4 + l4) ^ (r & 7)) * 8)]);
        }
      __builtin_amdgcn_s_setprio(1);
#pragma unroll
      for (int mi = 0; mi < 4; ++mi)
#pragma unroll
        for (int nj = 0; nj < 3; ++nj) {
          acc[q * 4 + mi][nj] = __builtin_amdgcn_mfma_f32_16x16x32_bf16(
              af[mi][0], bfr[nj][0], acc[q * 4 + mi][nj], 0, 0, 0);
          acc[q * 4 + mi][nj] = __builtin_amdgcn_mfma_f32_16x16x32_bf16(
              af[mi][1], bfr[nj][1], acc[q * 4 + mi][nj], 0, 0, 0);
        }
      __builtin_amdgcn_s_setprio(0);
    }
    // rule-18 fix: drain LDS reads and pin ALL ops before signaling barrier2.
    asm volatile("s_waitcnt lgkmcnt(0)" ::: "memory");
    __builtin_amdgcn_sched_barrier(0);
    __builtin_amdgcn_s_barrier();
    asm volatile("" ::: "memory");
    if (t + 2 < NT) STAGEQ(cur, (t + 2) << 6);
  }
#undef STAGEQ

#pragma unroll
  for (int a = 0; a < 8; ++a)
#pragma unroll
    for (int nj = 0; nj < 3; ++nj)
#pragma unroll
      for (int j = 0; j < 4; ++j) {
        const int m = m0 + wrH * 128 + (a >> 2) * 64 + (a & 3) * 16 + l4 * 4 + j;
        const int n = n0 + wc * 48 + nj * 16 + l15;
        C[(size_t)m * N + n] = __float2bfloat16(acc[a][nj][j]);
      }
}

// ------------- GEMM 256x128: C[M,N] = A[M,K]*B[N,K]^T, f32 out -------------
// 8 waves (4M x 2N), per-wave 64x64. Counted vmcnt: L = 4(A)+2(B) = 6 ->
// steady entry wait vmcnt(6); prefetch dist 2; raw s_barrier; T2 both-sides
// swizzle; rule-18 drain before barrier2. Grid = 256 blocks = 1 full wave.
__global__ __launch_bounds__(512, 1) void gemm_bt256x128f(const __hip_bfloat16* __restrict__ A,
                                                          const __hip_bfloat16* __restrict__ B,
                                                          float* __restrict__ C,
                                                          int M, int N, int K) {
  __shared__ __hip_bfloat16 As[2][256 * 64];   // 64 KB
  __shared__ __hip_bfloat16 Bs[2][128 * 64];   // 32 KB
  const int tid = threadIdx.x;
  const int lane = tid & 63;
  const int wid = tid >> 6;
  const int l15 = lane & 15, l4 = lane >> 4;
  const int wr = (wid >> 1) * 64;
  const int wc = (wid & 1) * 64;
  const int m0 = blockIdx.x * 256, n0 = blockIdx.y * 128;
  const int NT = K >> 6;
  f32x4 acc[4][4] = {};

#define STAGE2(buf, kt)                                                              \
  do {                                                                               \
    _Pragma("unroll")                                                                \
    for (int i_ = 0; i_ < 4; ++i_) {                                                 \
      const int slot_ = i_ * 512 + tid;                                              \
      const int row_ = slot_ >> 3, c8_ = slot_ & 7;                                  \
      const int gc_ = (c8_ ^ (row_ & 7)) * 8;                                        \
      __builtin_amdgcn_global_load_lds(                                              \
          GLB_AS(A + (size_t)(m0 + row_) * K + (kt) + gc_),                          \
          LDS_AS((char*)As[buf] + slot_ * 16), 16, 0, 0);                            \
    }                                                                                \
    _Pragma("unroll")                                                                \
    for (int i_ = 0; i_ < 2; ++i_) {                                                 \
      const int slot_ = i_ * 512 + tid;                                              \
      const int row_ = slot_ >> 3, c8_ = slot_ & 7;                                  \
      const int gc_ = (c8_ ^ (row_ & 7)) * 8;                                        \
      __builtin_amdgcn_global_load_lds(                                              \
          GLB_AS(B + (size_t)(n0 + row_) * K + (kt) + gc_),                          \
          LDS_AS((char*)Bs[buf] + slot_ * 16), 16, 0, 0);                            \
    }                                                                                \
  } while (0)

  STAGE2(0, 0);
  if (NT > 1) STAGE2(1, 64);

  for (int t = 0; t < NT; ++t) {
    const int cur = t & 1;
    if (t < NT - 1) asm volatile("s_waitcnt vmcnt(6)" ::: "memory");
    else            asm volatile("s_waitcnt vmcnt(0)" ::: "memory");
    __builtin_amdgcn_sched_barrier(0);
    __builtin_amdgcn_s_barrier();
    asm volatile("" ::: "memory");

#pragma unroll
    for (int kk = 0; kk < 2; ++kk) {
      bf16x8 af[4], bfr[4];
#pragma unroll
      for (int mi = 0; mi < 4; ++mi) {
        const int r = wr + mi * 16 + l15;
        af[mi] = *reinterpret_cast<const bf16x8*>(
            &As[cur][r * 64 + (((kk * 4 + l4) ^ (r & 7)) * 8)]);
      }
#pragma unroll
      for (int ni = 0; ni < 4; ++ni) {
        const int r = wc + ni * 16 + l15;
        bfr[ni] = *reinterpret_cast<const bf16x8*>(
            &Bs[cur][r * 64 + (((kk * 4 + l4) ^ (r & 7)) * 8)]);
      }
      __builtin_amdgcn_s_setprio(1);
#pragma unroll
      for (int mi = 0; mi < 4; ++mi)
#pragma unroll
        for (int ni = 0; ni < 4; ++ni)
          acc[mi][ni] = __builtin_amdgcn_mfma_f32_16x16x32_bf16(af[mi], bfr[ni], acc[mi][ni], 0, 0, 0);
      __builtin_amdgcn_s_setprio(0);
    }
    // rule-18 fix: drain LDS reads before signaling barrier2.
    asm volatile("s_waitcnt lgkmcnt(0)" ::: "memory");
    __builtin_amdgcn_sched_barrier(0);
    __builtin_amdgcn_s_barrier();
    asm volatile("" ::: "memory");
    if (t + 2 < NT) STAGE2(cur, (t + 2) << 6);
  }
#undef STAGE2

#pragma unroll
  for (int mi = 0; mi < 4; ++mi)
#pragma unroll
    for (int ni = 0; ni < 4; ++ni)
#pragma unroll
      for (int j = 0; j < 4; ++j) {
        const int m = m0 + wr + mi * 16 + l4 * 4 + j;
        const int n = n0 + wc + ni * 16 + l15;
        C[(size_t)m * N + n] = acc[mi][ni][j];
      }
}

// --------------------------- causal flash attn -----------------------------
// R6 config (best measured over 6 structural variants). 512 threads = 8
// waves; waves 0-3 own 256-row q-tile x, waves 4-7 own 7-x (uniform per-SIMD
// work); 4 Q-frags/wave; grid 256 = 1 block/CU. NOW (512,1): grid already
// caps residency at 1 block/CU, so the (512,2) 128-VGPR cap only squeezed
// the allocator (was 124/128) -- lift it to the 256-reg budget.
// P-fence: lgkmcnt(0) memory fence only (write->read are both memory ops;
// the rule-18 reg-hoist hazard doesn't apply -- PV MFMAs depend on loads
// issued AFTER the fence). Ran R5-R13 in this form incl. post-timing checks.
__global__ __launch_bounds__(512, 1) void attn_causal(const __hip_bfloat16* __restrict__ qkv,
                                                      __hip_bfloat16* __restrict__ o) {
  constexpr int T = 2048, F = 3072, C = 1024;
  __shared__ __hip_bfloat16 Ks[2][64 * 72];
  __shared__ __hip_bfloat16 Vts[2][64 * 72];
  __shared__ __hip_bfloat16 Ps[8][16 * 72];
  const int tid = threadIdx.x;
  const int wid = tid >> 6, lane = tid & 63;
  const int l15 = lane & 15, l4 = lane >> 4;
  const int x = blockIdx.x, h = blockIdx.y, b = blockIdx.z;
  const int qt = (wid < 4) ? x : (7 - x);
  const int nt = 4 * (7 - x) + 4;
  const int tmax = 4 * qt + (wid & 3);
  const int hoff = h * 64;
  const __hip_bfloat16* base = qkv + (size_t)b * T * F;
  const int Q0 = qt * 256 + (wid & 3) * 64;

  constexpr float SC = 0.125f * 1.44269504088896f;

  bf16x8 aq[4][2];
#pragma unroll
  for (int f = 0; f < 4; ++f)
#pragma unroll
    for (int kk = 0; kk < 2; ++kk) {
      bf16x8 q = *reinterpret_cast<const bf16x8*>(base + (size_t)(Q0 + f * 16 + l15) * F + hoff + kk * 32 + l4 * 8);
#pragma unroll
      for (int e = 0; e < 8; ++e) {
        const unsigned short raw = (unsigned short)q[e];
        const float fv = __uint_as_float((unsigned)raw << 16) * SC;
        __hip_bfloat16 qs = __float2bfloat16(fv);
        q[e] = *reinterpret_cast<short*>(&qs);
      }
      aq[f][kk] = q;
    }

  f32x4 acc[4][4] = {};
  float mrun[4], lrun[4];
#pragma unroll
  for (int f = 0; f < 4; ++f) { mrun[f] = -1e30f; lrun[f] = 0.f; }

  const int sV = tid;
  const int sK = tid - 256;
  bf16x8 sreg0, sreg1;
  if (wid < 4) {
    const size_t vr = (size_t)(2 * (sV >> 3)) * F + hoff + 2 * C + (sV & 7) * 8;
    sreg0 = *reinterpret_cast<const bf16x8*>(base + vr);
    sreg1 = *reinterpret_cast<const bf16x8*>(base + vr + F);
  } else {
    sreg0 = *reinterpret_cast<const bf16x8*>(base + (size_t)(sK >> 3) * F + hoff + C + (sK & 7) * 8);
    sreg1 = *reinterpret_cast<const bf16x8*>(base + (size_t)(32 + (sK >> 3)) * F + hoff + C + (sK & 7) * 8);
  }

  for (int t = 0; t < nt; ++t) {
    const int cur = t & 1;
    if (wid < 4) {
      const unsigned short* a0 = reinterpret_cast<const unsigned short*>(&sreg0);
      const unsigned short* a1 = reinterpret_cast<const unsigned short*>(&sreg1);
      const int c8 = sV & 7, r2 = sV >> 3;
      unsigned pk[8], tw[8], pkr[8];
#pragma unroll
      for (int j = 0; j < 8; ++j) pk[j] = (unsigned)a0[j] | ((unsigned)a1[j] << 16);
#pragma unroll
      for (int j = 0; j < 8; ++j) tw[j] = (c8 & 4) ? pk[(j + 4) & 7] : pk[j];
#pragma unroll
      for (int j = 0; j < 8; ++j) pkr[j] = (c8 & 2) ? tw[(j + 2) & 7] : tw[j];
#pragma unroll
      for (int j = 0; j < 8; ++j) tw[j] = (c8 & 1) ? pkr[(j + 1) & 7] : pkr[j];
#pragma unroll
      for (int jj = 0; jj < 8; ++jj) {
        const int d = c8 * 8 + ((jj + c8) & 7);
        *reinterpret_cast<unsigned*>(&Vts[cur][d * 72 + 2 * r2]) = tw[jj];
      }
    } else {
      *reinterpret_cast<bf16x8*>(&Ks[cur][(sK >> 3) * 72 + (sK & 7) * 8]) = sreg0;
      *reinterpret_cast<bf16x8*>(&Ks[cur][(32 + (sK >> 3)) * 72 + (sK & 7) * 8]) = sreg1;
    }
    __syncthreads();
    if (t + 1 < nt) {
      const int kn = (t + 1) * 64;
      if (wid < 4) {
        const size_t vr = (size_t)(kn + 2 * (sV >> 3)) * F + hoff + 2 * C + (sV & 7) * 8;
        sreg0 = *reinterpret_cast<const bf16x8*>(base + vr);
        sreg1 = *reinterpret_cast<const bf16x8*>(base + vr + F);
      } else {
        sreg0 = *reinterpret_cast<const bf16x8*>(base + (size_t)(kn + (sK >> 3)) * F + hoff + C + (sK & 7) * 8);
        sreg1 = *reinterpret_cast<const bf16x8*>(base + (size_t)(kn + 32 + (sK >> 3)) * F + hoff + C + (sK & 7) * 8);
      }
    }
    if (t > tmax) continue;
    const bool diag = (t == tmax);

    bf16x8 kf[4][2], vf[4][2];
#pragma unroll
    for (int kt = 0; kt < 4; ++kt)
#pragma unroll
      for (int kk = 0; kk < 2; ++kk)
        kf[kt][kk] = *reinterpret_cast<const bf16x8*>(&Ks[cur][(kt * 16 + l15) * 72 + kk * 32 + l4 * 8]);
#pragma unroll
    for (int di = 0; di < 4; ++di)
#pragma unroll
      for (int kk = 0; kk < 2; ++kk)
        vf[di][kk] = *reinterpret_cast<const bf16x8*>(&Vts[cur][(di * 16 + l15) * 72 + kk * 32 + l4 * 8]);

    __hip_bfloat16* pw = Ps[wid];
#pragma unroll
    for (int f = 0; f < 4; ++f) {
      f32x4 s[4];
#pragma unroll
      for (int kt = 0; kt < 4; ++kt) {
        f32x4 z = {};
        z = __builtin_amdgcn_mfma_f32_16x16x32_bf16(kf[kt][0], aq[f][0], z, 0, 0, 0);
        z = __builtin_amdgcn_mfma_f32_16x16x32_bf16(kf[kt][1], aq[f][1], z, 0, 0, 0);
        s[kt] = z;
      }
      if (diag) {
        const int ql = f * 16 + l15;
#pragma unroll
        for (int kt = 0; kt < 4; ++kt)
#pragma unroll
          for (int j = 0; j < 4; ++j) {
            const int kvl = kt * 16 + l4 * 4 + j;
            s[kt][j] = (kvl <= ql) ? s[kt][j] : -1e30f;
          }
      }

      float t0 = fmaxf(fmaxf(s[0][0], s[0][1]), s[0][2]);
      float t1 = fmaxf(fmaxf(s[0][3], s[1][0]), s[1][1]);
      float t2 = fmaxf(fmaxf(s[1][2], s[1][3]), s[2][0]);
      float t3 = fmaxf(fmaxf(s[2][1], s[2][2]), s[2][3]);
      float t4 = fmaxf(fmaxf(s[3][0], s[3][1]), s[3][2]);
      float mt = fmaxf(fmaxf(fmaxf(t0, t1), fmaxf(t2, t3)), fmaxf(t4, s[3][3]));
      mt = fmaxf(mt, __shfl_xor(mt, 16, 64));
      mt = fmaxf(mt, __shfl_xor(mt, 32, 64));
      const bool defer = __all(mt <= mrun[f] + 8.f);
      const float mnew = defer ? mrun[f] : fmaxf(mrun[f], mt);
      float rs = 0.f;
#pragma unroll
      for (int kt = 0; kt < 4; ++kt) {
        float p0 = exp2f(s[kt][0] - mnew), p1 = exp2f(s[kt][1] - mnew);
        float p2 = exp2f(s[kt][2] - mnew), p3 = exp2f(s[kt][3] - mnew);
        s[kt][0] = p0; s[kt][1] = p1; s[kt][2] = p2; s[kt][3] = p3;
        rs += (p0 + p1) + (p2 + p3);
      }
      rs += __shfl_xor(rs, 16, 64);
      rs += __shfl_xor(rs, 32, 64);
      if (defer) {
        lrun[f] += rs;
      } else {
        const float sco = exp2f(mrun[f] - mnew);
        lrun[f] = lrun[f] * sco + rs;
        mrun[f] = mnew;
#pragma unroll
        for (int di = 0; di < 4; ++di) acc[f][di] *= sco;
      }

#pragma unroll
      for (int kt = 0; kt < 4; ++kt) {
        unsigned w0, w1;
        asm("v_cvt_pk_bf16_f32 %0, %1, %2" : "=v"(w0) : "v"(s[kt][0]), "v"(s[kt][1]));
        asm("v_cvt_pk_bf16_f32 %0, %1, %2" : "=v"(w1) : "v"(s[kt][2]), "v"(s[kt][3]));
        unsigned long long dw = (unsigned long long)w0 | ((unsigned long long)w1 << 32);
        *reinterpret_cast<unsigned long long*>(&pw[l15 * 72 + kt * 16 + l4 * 4]) = dw;
      }
      // memory fence: P writes complete before the reads below (both are
      // memory ops -> the clobber orders them; reg-hoist hazard N/A here).
      asm volatile("s_waitcnt lgkmcnt(0)" ::: "memory");
      bf16x8 pa0 = *reinterpret_cast<const bf16x8*>(pw + l15 * 72 + l4 * 8);
      bf16x8 pa1 = *reinterpret_cast<const bf16x8*>(pw + l15 * 72 + 32 + l4 * 8);

#pragma unroll
      for (int di = 0; di < 4; ++di) {
        acc[f][di] = __builtin_amdgcn_mfma_f32_16x16x32_bf16(vf[di][0], pa0, acc[f][di], 0, 0, 0);
        acc[f][di] = __builtin_amdgcn_mfma_f32_16x16x32_bf16(vf[di][1], pa1, acc[f][di], 0, 0, 0);
      }
    }
  }

#pragma unroll
  for (int f = 0; f < 4; ++f) {
    const float inv = 1.0f / lrun[f];
    __hip_bfloat16* op = o + (size_t)((size_t)b * T + Q0 + f * 16 + l15) * C + hoff;
#pragma unroll
    for (int di = 0; di < 4; ++di) {
      ushort4 u;
      __hip_bfloat16 e0 = __float2bfloat16(acc[f][di][0] * inv);
      __hip_bfloat16 e1 = __float2bfloat16(acc[f][di][1] * inv);
      __hip_bfloat16 e2 = __float2bfloat16(acc[f][di][2] * inv);
      __hip_bfloat16 e3 = __float2bfloat16(acc[f][di][3] * inv);
      u.x = *reinterpret_cast<unsigned short*>(&e0);
      u.y = *reinterpret_cast<unsigned short*>(&e1);
      u.z = *reinterpret_cast<unsigned short*>(&e2);
      u.w = *reinterpret_cast<unsigned short*>(&e3);
      *reinterpret_cast<ushort4*>(op + di * 16 + l4 * 4) = u;
    }
  }
}

// ------------------------------- launcher ----------------------------------
extern "C" void kernel_launch(void* const* d_in, const int* in_sizes, int n_in,
                              void* d_out, int out_size, void* d_ws, size_t ws_size,
                              hipStream_t stream) {
  const float* x = (const float*)d_in[0];
  const float* w_qkv = (const float*)d_in[1];
  const float* w_out = (const float*)d_in[2];
  float* out = (float*)d_out;

  constexpr int B = 4, T = 2048, C = 1024, F = 3 * C;
  constexpr int M = B * T;

  __hip_bfloat16* xb = (__hip_bfloat16*)d_ws;            // M*C
  __hip_bfloat16* wqkvb = xb + (size_t)M * C;            // F*C
  __hip_bfloat16* woutb = wqkvb + (size_t)F * C;         // C*C
  __hip_bfloat16* qkvb = woutb + (size_t)C * C;          // M*F
  __hip_bfloat16* attnb = qkvb + (size_t)M * F;          // M*C

  constexpr int na4 = M * C / 4, nb4 = F * C / 4, nc4 = C * C / 4;
  cvt3_f32_bf16<<<2048, 256, 0, stream>>>(x, w_qkv, w_out, xb, wqkvb, woutb, na4, nb4, nc4);

  gemm_bt256x192<<<dim3(M / 256, F / 192), 512, 0, stream>>>(xb, wqkvb, qkvb, M, F, C);

  attn_causal<<<dim3(4, 16, B), 512, 0, stream>>>(qkvb, attnb);

  gemm_bt256x128f<<<dim3(M / 256, C / 128), 512, 0, stream>>>(attnb, woutb, out, M, C, C);
}